// Round 16
// baseline (257.136 us; speedup 1.0000x reference)
//
#include <hip/hip_runtime.h>
#include <hip/hip_fp16.h>

#define HID 128
#define INF 500
#define NCLS 16
#define PW  112    // projected width: [s0 | p1 q3a q4a | p2 q3b q4b]
#define BKLG 8
#define BKW 256    // rows per bucket
#define NB1 128    // partition blocks, matrix 1
#define NB2 192    // partition blocks, matrix 2

typedef __attribute__((ext_vector_type(8))) short short8v;
typedef __attribute__((ext_vector_type(4))) float f32x4;
typedef __attribute__((ext_vector_type(4))) float f4v;   // native vec for nontemporal builtins

// split fp32 into hi (truncated bf16) + lo (bf16 of remainder)
__device__ __forceinline__ void split_bf16(float v, unsigned short& h, unsigned short& l) {
  unsigned u = __float_as_uint(v);
  h = (unsigned short)(u >> 16);
  float hf = __uint_as_float(u & 0xFFFF0000u);
  l = (unsigned short)(__float_as_uint(v - hf) >> 16);
}

__device__ __forceinline__ void cvt8v(f4v c0, f4v c1, short8v& h8, short8v& l8) {
#pragma unroll
  for (int j = 0; j < 8; ++j) {
    float v = (j < 4) ? c0[j] : c1[j - 4];
    unsigned short h, l;
    split_bf16(v, h, l);
    h8[j] = (short)h;
    l8[j] = (short)l;
  }
}

// ---------------- weight prep (also zeroes bucket-total counters) ----------------
__global__ __launch_bounds__(256) void prep_w(
    const float* __restrict__ we, const float* __restrict__ wc,
    unsigned short* __restrict__ wh, unsigned short* __restrict__ wl,
    unsigned short* __restrict__ ch, unsigned short* __restrict__ cl,
    int* __restrict__ btz) {
  const int bid = blockIdx.x;
  if (bid == 0) {  // zero bt1+bt2 (1024 ints, adjacent) - replaces SDMA memset node
    for (int i = threadIdx.x; i < 1024; i += 256) btz[i] = 0;
  }
  if (bid < 256) {
    int idx = bid * 256 + threadIdx.x;     // < 512*128
    int k = idx >> 7, nn = idx & 127;
    float v = (k < INF) ? we[k * HID + nn] : 0.f;
    unsigned short h, l;
    split_bf16(v, h, l);
    int kstep = k >> 5, ks = k & 31;
    int lane = (nn & 15) | ((ks >> 3) << 4);
    int j = ks & 7, nf = nn >> 4;
    size_t o = (((size_t)(kstep * 8 + nf)) * 64 + lane) * 8 + j;
    wh[o] = h;
    wl[o] = l;
  } else {
    int idx = (bid - 256) * 256 + threadIdx.x;
    if (idx >= HID * PW) return;
    int k = idx / PW, np = idx % PW;
    int o = np >> 4;
    int blk = (o == 0) ? 0 : ((o < 4) ? (2 * o - 1) : (2 * o - 6));
    float v = wc[(blk * HID + k) * NCLS + (np & 15)];
    unsigned short h, l;
    split_bf16(v, h, l);
    int kstep = k >> 5, ks = k & 31;
    int lane = (np & 15) | ((ks >> 3) << 4);
    int j = ks & 7, nf = np >> 4;
    size_t of = (((size_t)(kstep * 7 + nf)) * 64 + lane) * 8 + j;
    ch[of] = h;
    cl[of] = l;
  }
}

// ---------------- embed MFMA: r0 = relu(x @ we), bf16x3, nf-split 4-wave blocks ----------------
// 64 rows/block, 256 threads = 4 waves: wave(pair,nfh) computes rows [pair*32,+32) x cols [nfh*64,+64).
// Same x-tile traffic, same B traffic, 2x the waves -> grid 782 blocks gives 12 waves/CU (was 6).
__global__ __launch_bounds__(256) void embed_mfma(
    const float* __restrict__ x, const unsigned short* __restrict__ wh,
    const unsigned short* __restrict__ wl, unsigned short* __restrict__ r0h,
    unsigned short* __restrict__ r0l, int n) {
  const int tid = threadIdx.x;
  const int wave = tid >> 6, lane = tid & 63;
  const int pair = wave >> 1;   // which 32-row tile
  const int nfh = wave & 1;     // which 64-col (4-nf) half
  const int row0 = blockIdx.x * 64;
  const int rA = lane & 15, kg = lane >> 4;

  __shared__ float xs[64][68];   // 17.4 KB

  f32x4 acc[2][4];
#pragma unroll
  for (int rf = 0; rf < 2; ++rf)
#pragma unroll
    for (int nfl = 0; nfl < 4; ++nfl)
#pragma unroll
      for (int r = 0; r < 4; ++r) acc[rf][nfl][r] = 0.f;

  f4v pf[4];
#define LOAD_TILE(kt)                                                         \
  {                                                                           \
    const int k0_ = (kt) * 64;                                                \
    _Pragma("unroll")                                                         \
    for (int q = 0; q < 4; ++q) {                                             \
      int i_ = tid + q * 256;                                                 \
      int r_ = i_ >> 4, pos_ = i_ & 15;                                       \
      int gr_ = min(row0 + r_, n - 1);                                        \
      int gk_ = k0_ + pos_ * 4;                                               \
      pf[q] = (gk_ + 4 <= INF)                                                \
                  ? __builtin_nontemporal_load(                               \
                        (const f4v*)&x[(size_t)gr_ * INF + gk_])              \
                  : (f4v)(0.f);                                               \
    }                                                                         \
  }

  LOAD_TILE(0);
  for (int kt = 0; kt < 8; ++kt) {
#pragma unroll
    for (int q = 0; q < 4; ++q) {
      int i = tid + q * 256;
      *(f4v*)&xs[i >> 4][(i & 15) * 4] = pf[q];
    }
    __syncthreads();
    if (kt < 7) LOAD_TILE(kt + 1);   // next-tile loads in flight under compute

#pragma unroll
    for (int kh2 = 0; kh2 < 2; ++kh2) {
      const int kb = kh2 * 32 + kg * 8;
      short8v ah[2], al[2];
#pragma unroll
      for (int rf = 0; rf < 2; ++rf) {
        const int rl = pair * 32 + rf * 16 + rA;
        f4v c0 = *(const f4v*)&xs[rl][kb];
        f4v c1 = *(const f4v*)&xs[rl][kb + 4];
        cvt8v(c0, c1, ah[rf], al[rf]);
      }
      const size_t bbase = ((size_t)((kt * 2 + kh2) * 8) * 64 + lane) * 8;
      short8v Bh[4], Bl[4];
#pragma unroll
      for (int nfl = 0; nfl < 4; ++nfl) {
        Bh[nfl] = *(const short8v*)&wh[bbase + (size_t)(nfh * 4 + nfl) * 512];
        Bl[nfl] = *(const short8v*)&wl[bbase + (size_t)(nfh * 4 + nfl) * 512];
      }
#pragma unroll
      for (int nfl = 0; nfl < 4; ++nfl)
#pragma unroll
        for (int rf = 0; rf < 2; ++rf) {
          acc[rf][nfl] = __builtin_amdgcn_mfma_f32_16x16x32_bf16(ah[rf], Bh[nfl], acc[rf][nfl], 0, 0, 0);
          acc[rf][nfl] = __builtin_amdgcn_mfma_f32_16x16x32_bf16(ah[rf], Bl[nfl], acc[rf][nfl], 0, 0, 0);
          acc[rf][nfl] = __builtin_amdgcn_mfma_f32_16x16x32_bf16(al[rf], Bh[nfl], acc[rf][nfl], 0, 0, 0);
        }
    }
    __syncthreads();
  }
#undef LOAD_TILE

#pragma unroll
  for (int rf = 0; rf < 2; ++rf)
#pragma unroll
    for (int nfl = 0; nfl < 4; ++nfl) {
      const int row = row0 + pair * 32 + rf * 16 + kg * 4;
      const int col = (nfh * 4 + nfl) * 16 + rA;
#pragma unroll
      for (int r = 0; r < 4; ++r) {
        if (row + r < n) {
          float v = fmaxf(acc[rf][nfl][r], 0.f);
          unsigned short h, l;
          split_bf16(v, h, l);
          r0h[(size_t)(row + r) * HID + col] = h;
          r0l[(size_t)(row + r) * HID + col] = l;
        }
      }
    }
}

// ---------------- proj MFMA: [s0|Pa1|Pa2] = r0 @ wcP, bf16x3, 4 waves x 16 rows ----------------
__global__ __launch_bounds__(256) void proj_mfma(
    const unsigned short* __restrict__ r0h, const unsigned short* __restrict__ r0l,
    const unsigned short* __restrict__ ch, const unsigned short* __restrict__ cl,
    float* __restrict__ s0f, __half* __restrict__ Pa1, __half* __restrict__ Pa2, int n) {
  const int wave = threadIdx.x >> 6, lane = threadIdx.x & 63;
  const int row0 = blockIdx.x * 64 + wave * 16;
  const int rA = lane & 15, kg = lane >> 4;

  f32x4 acc[7];
#pragma unroll
  for (int nf = 0; nf < 7; ++nf)
#pragma unroll
    for (int r = 0; r < 4; ++r) acc[nf][r] = 0.f;

  const unsigned short* arh = &r0h[(size_t)min(row0 + rA, n - 1) * HID];
  const unsigned short* arl = &r0l[(size_t)min(row0 + rA, n - 1) * HID];

#pragma unroll
  for (int kstep = 0; kstep < 4; ++kstep) {
    const int kb = kstep * 32 + kg * 8;
    short8v ah = __builtin_nontemporal_load((const short8v*)&arh[kb]);
    short8v al = __builtin_nontemporal_load((const short8v*)&arl[kb]);

    const size_t bbase = ((size_t)kstep * 7 * 64 + lane) * 8;
    short8v Bh[7], Bl[7];
#pragma unroll
    for (int nf = 0; nf < 7; ++nf) {
      Bh[nf] = *(const short8v*)&ch[bbase + (size_t)nf * 512];
      Bl[nf] = *(const short8v*)&cl[bbase + (size_t)nf * 512];
    }
#pragma unroll
    for (int nf = 0; nf < 7; ++nf) {
      acc[nf] = __builtin_amdgcn_mfma_f32_16x16x32_bf16(ah, Bh[nf], acc[nf], 0, 0, 0);
      acc[nf] = __builtin_amdgcn_mfma_f32_16x16x32_bf16(ah, Bl[nf], acc[nf], 0, 0, 0);
      acc[nf] = __builtin_amdgcn_mfma_f32_16x16x32_bf16(al, Bh[nf], acc[nf], 0, 0, 0);
    }
  }

#pragma unroll
  for (int nf = 0; nf < 7; ++nf) {
    const int row = row0 + kg * 4;
#pragma unroll
    for (int r = 0; r < 4; ++r) {
      if (row + r < n) {
        float v = acc[nf][r];
        size_t ro = (size_t)(row + r) * 16 + rA;
        if (nf == 0) {
          s0f[ro] = v;
        } else if (nf < 4) {
          Pa1[ro * 4 + (nf - 1)] = __float2half(v);
          if (nf == 1) Pa1[ro * 4 + 3] = __float2half(0.f);
        } else {
          Pa2[ro * 4 + (nf - 4)] = __float2half(v);
          if (nf == 4) Pa2[ro * 4 + 3] = __float2half(0.f);
        }
      }
    }
  }
}

// ---------------- radix partition ----------------
__global__ __launch_bounds__(256) void part_hist(
    const int* __restrict__ r1, int e1, const int* __restrict__ r2, int e2,
    int* __restrict__ g1, int* __restrict__ g2,
    int* __restrict__ bt1, int* __restrict__ bt2, int nbk) {
  const int m = blockIdx.y;
  const int NB = m ? NB2 : NB1;
  const int b = blockIdx.x;
  if (b >= NB) return;
  const int* rows = m ? r2 : r1;
  const int E = m ? e2 : e1;
  int* g = m ? g2 : g1;
  int* bt = m ? bt2 : bt1;
  __shared__ int h[512];
  for (int i = threadIdx.x; i < nbk; i += 256) h[i] = 0;
  __syncthreads();
  const int ch = (E + NB - 1) / NB;
  const int lo = b * ch, hi = min(lo + ch, E);
  for (int i = lo + threadIdx.x; i < hi; i += 256)
    atomicAdd(&h[rows[i] >> BKLG], 1);
  __syncthreads();
  for (int k = threadIdx.x; k < nbk; k += 256) {
    g[(size_t)k * NB + b] = h[k];
    if (h[k]) atomicAdd(&bt[k], h[k]);
  }
}

// scan bucket totals -> exclusive bucket bases (1 block per matrix)
__global__ __launch_bounds__(256) void scan_bt(
    const int* __restrict__ bt1, int* __restrict__ ebt1,
    const int* __restrict__ bt2, int* __restrict__ ebt2, int nbk) {
  const int* bt = blockIdx.x ? bt2 : bt1;
  int* ebt = blockIdx.x ? ebt2 : ebt1;
  __shared__ int sh[256];
  const int t = threadIdx.x;
  int v = (t < nbk) ? bt[t] : 0;
  sh[t] = v;
  __syncthreads();
  for (int d = 1; d < 256; d <<= 1) {
    int u = (t >= d) ? sh[t - d] : 0;
    __syncthreads();
    sh[t] += u;
    __syncthreads();
  }
  if (t < nbk) ebt[t] = sh[t] - v;
}

// per-bucket scan of per-block counts -> global offsets (parallel over buckets)
__global__ __launch_bounds__(256) void offs_scan(
    int* __restrict__ g1, const int* __restrict__ ebt1,
    int* __restrict__ g2, const int* __restrict__ ebt2, int nbk) {
  const int m = blockIdx.y;
  const int NB = m ? NB2 : NB1;
  int* g = m ? g2 : g1;
  const int* ebt = m ? ebt2 : ebt1;
  const int k = blockIdx.x;
  __shared__ int sh[256];
  const int t = threadIdx.x;
  int v = (t < NB) ? g[(size_t)k * NB + t] : 0;
  sh[t] = v;
  __syncthreads();
  for (int d = 1; d < 256; d <<= 1) {
    int u = (t >= d) ? sh[t - d] : 0;
    __syncthreads();
    sh[t] += u;
    __syncthreads();
  }
  if (t < NB) g[(size_t)k * NB + t] = ebt[k] + sh[t] - v;
}

// scatter: block b's writes to bucket k form one contiguous run (write-amp ~1x)
__global__ __launch_bounds__(256) void part_scatter(
    const int* __restrict__ r1, const int* __restrict__ c1, const float* __restrict__ v1, int e1,
    const int* __restrict__ r2, const int* __restrict__ c2, const float* __restrict__ v2, int e2,
    const int* __restrict__ g1, const int* __restrict__ g2,
    int2* __restrict__ pack1, int2* __restrict__ pack2, int nbk) {
  const int m = blockIdx.y;
  const int NB = m ? NB2 : NB1;
  const int b = blockIdx.x;
  if (b >= NB) return;
  const int* rows = m ? r2 : r1;
  const int* cols = m ? c2 : c1;
  const float* vals = m ? v2 : v1;
  const int E = m ? e2 : e1;
  const int* g = m ? g2 : g1;
  int2* pack = m ? pack2 : pack1;
  __shared__ int lcur[512];
  for (int k = threadIdx.x; k < nbk; k += 256) lcur[k] = g[(size_t)k * NB + b];
  __syncthreads();
  const int ch = (E + NB - 1) / NB;
  const int lo = b * ch, hi = min(lo + ch, E);
  for (int i = lo + threadIdx.x; i < hi; i += 256) {
    int r = rows[i];
    int pos = atomicAdd(&lcur[r >> BKLG], 1);
    unsigned u = (unsigned)(vals[i] * 65536.0f);
    if (u > 65535u) u = 65535u;
    pack[pos] = make_int2(cols[i] | ((r & (BKW - 1)) << 16), (int)u);
  }
}

// per-bucket LDS counting sort (256 rows) -> row-sorted 4B edges + per-row rp
__global__ __launch_bounds__(256) void bucket_sort(
    const int2* __restrict__ pack1, const int* __restrict__ g1,
    unsigned* __restrict__ srt1, int* __restrict__ rp1, int e1,
    const int2* __restrict__ pack2, const int* __restrict__ g2,
    unsigned* __restrict__ srt2, int* __restrict__ rp2, int e2,
    int n, int nbk) {
  const int m = blockIdx.y;
  const int NB = m ? NB2 : NB1;
  const int2* pack = m ? pack2 : pack1;
  const int* g = m ? g2 : g1;
  unsigned* srt = m ? srt2 : srt1;
  int* rp = m ? rp2 : rp1;
  const int E = m ? e2 : e1;
  const int k = blockIdx.x;
  const int base = g[(size_t)k * NB];
  const int end = (k + 1 < nbk) ? g[(size_t)(k + 1) * NB] : E;
  __shared__ int lcnt[256], lws[256], lcur[256];
  const int t = threadIdx.x;
  lcnt[t] = 0;
  __syncthreads();
  for (int i = base + t; i < end; i += 256)
    atomicAdd(&lcnt[(pack[i].x >> 16) & (BKW - 1)], 1);
  __syncthreads();
  int s = lcnt[t];
  lws[t] = s;
  __syncthreads();
  for (int d = 1; d < 256; d <<= 1) {
    int v = (t >= d) ? lws[t - d] : 0;
    __syncthreads();
    lws[t] += v;
    __syncthreads();
  }
  int excl = base + lws[t] - s;
  lcur[t] = excl;
  int row = k * BKW + t;
  if (row < n) rp[row] = excl;
  if (k == nbk - 1 && t == 0) rp[n] = E;
  __syncthreads();
  for (int i = base + t; i < end; i += 256) {
    int2 e = pack[i];
    int pos = atomicAdd(&lcur[(e.x >> 16) & (BKW - 1)], 1);
    srt[pos] = (unsigned)(e.x & 0xFFFF) | ((unsigned)e.y << 16);
  }
}

__device__ __forceinline__ float dec_val(unsigned e) {
  return ((float)(e >> 16) + 0.5f) * (1.0f / 65536.0f);
}

// ---------------- fused SpMM (both matrices, 48-wide) + combine ----------------
__global__ __launch_bounds__(256) void spmm48_both(
    const unsigned* __restrict__ srt1, const int* __restrict__ rp1,
    const unsigned* __restrict__ srt2, const int* __restrict__ rp2,
    const __half* __restrict__ Pa1, const __half* __restrict__ Pa2,
    const float* __restrict__ s0f, float* __restrict__ wsum,
    __half* __restrict__ m3h, __half* __restrict__ m4h, int n) {
  const int row = blockIdx.x * 4 + (threadIdx.x >> 6);
  if (row >= n) return;
  const int lane = threadIdx.x & 63;
  const int c = lane & 15, g = lane >> 4;
  float a0 = 0.f, a1 = 0.f, a2 = 0.f, b0 = 0.f, b1 = 0.f, b2 = 0.f;
  {
    const int j0 = rp1[row], j1 = rp1[row + 1];
    if (j1 > j0) {
      const int nit = (j1 - j0 + 15) >> 4;
      int j = j0 + g;
      for (int it = 0; it < nit; ++it, j += 16) {
        int jj0 = min(j, j1 - 1), jj1 = min(j + 4, j1 - 1);
        int jj2 = min(j + 8, j1 - 1), jj3 = min(j + 12, j1 - 1);
        unsigned e0 = __builtin_nontemporal_load(&srt1[jj0]);
        unsigned e1 = __builtin_nontemporal_load(&srt1[jj1]);
        unsigned e2 = __builtin_nontemporal_load(&srt1[jj2]);
        unsigned e3 = __builtin_nontemporal_load(&srt1[jj3]);
        float2 r0 = *(const float2*)(Pa1 + ((size_t)(e0 & 0xFFFF) * 16 + c) * 4);
        float2 r1 = *(const float2*)(Pa1 + ((size_t)(e1 & 0xFFFF) * 16 + c) * 4);
        float2 r2 = *(const float2*)(Pa1 + ((size_t)(e2 & 0xFFFF) * 16 + c) * 4);
        float2 r3 = *(const float2*)(Pa1 + ((size_t)(e3 & 0xFFFF) * 16 + c) * 4);
        float v0 = (j < j1) ? dec_val(e0) : 0.f;
        float v1 = (j + 4 < j1) ? dec_val(e1) : 0.f;
        float v2 = (j + 8 < j1) ? dec_val(e2) : 0.f;
        float v3 = (j + 12 < j1) ? dec_val(e3) : 0.f;
        float2 f00 = __half22float2(*(__half2*)&r0.x), f01 = __half22float2(*(__half2*)&r0.y);
        float2 f10 = __half22float2(*(__half2*)&r1.x), f11 = __half22float2(*(__half2*)&r1.y);
        float2 f20 = __half22float2(*(__half2*)&r2.x), f21 = __half22float2(*(__half2*)&r2.y);
        float2 f30 = __half22float2(*(__half2*)&r3.x), f31 = __half22float2(*(__half2*)&r3.y);
        a0 += v0 * f00.x + v1 * f10.x + v2 * f20.x + v3 * f30.x;
        a1 += v0 * f00.y + v1 * f10.y + v2 * f20.y + v3 * f30.y;
        a2 += v0 * f01.x + v1 * f11.x + v2 * f21.x + v3 * f31.x;
      }
    }
  }
  {
    const int j0 = rp2[row], j1 = rp2[row + 1];
    if (j1 > j0) {
      const int nit = (j1 - j0 + 15) >> 4;
      int j = j0 + g;
      for (int it = 0; it < nit; ++it, j += 16) {
        int jj0 = min(j, j1 - 1), jj1 = min(j + 4, j1 - 1);
        int jj2 = min(j + 8, j1 - 1), jj3 = min(j + 12, j1 - 1);
        unsigned e0 = __builtin_nontemporal_load(&srt2[jj0]);
        unsigned e1 = __builtin_nontemporal_load(&srt2[jj1]);
        unsigned e2 = __builtin_nontemporal_load(&srt2[jj2]);
        unsigned e3 = __builtin_nontemporal_load(&srt2[jj3]);
        float2 r0 = *(const float2*)(Pa2 + ((size_t)(e0 & 0xFFFF) * 16 + c) * 4);
        float2 r1 = *(const float2*)(Pa2 + ((size_t)(e1 & 0xFFFF) * 16 + c) * 4);
        float2 r2 = *(const float2*)(Pa2 + ((size_t)(e2 & 0xFFFF) * 16 + c) * 4);
        float2 r3 = *(const float2*)(Pa2 + ((size_t)(e3 & 0xFFFF) * 16 + c) * 4);
        float v0 = (j < j1) ? dec_val(e0) : 0.f;
        float v1 = (j + 4 < j1) ? dec_val(e1) : 0.f;
        float v2 = (j + 8 < j1) ? dec_val(e2) : 0.f;
        float v3 = (j + 12 < j1) ? dec_val(e3) : 0.f;
        float2 f00 = __half22float2(*(__half2*)&r0.x), f01 = __half22float2(*(__half2*)&r0.y);
        float2 f10 = __half22float2(*(__half2*)&r1.x), f11 = __half22float2(*(__half2*)&r1.y);
        float2 f20 = __half22float2(*(__half2*)&r2.x), f21 = __half22float2(*(__half2*)&r2.y);
        float2 f30 = __half22float2(*(__half2*)&r3.x), f31 = __half22float2(*(__half2*)&r3.y);
        b0 += v0 * f00.x + v1 * f10.x + v2 * f20.x + v3 * f30.x;
        b1 += v0 * f00.y + v1 * f10.y + v2 * f20.y + v3 * f30.y;
        b2 += v0 * f01.x + v1 * f11.x + v2 * f21.x + v3 * f31.x;
      }
    }
  }
  a0 += __shfl_xor(a0, 16); a0 += __shfl_xor(a0, 32);
  a1 += __shfl_xor(a1, 16); a1 += __shfl_xor(a1, 32);
  a2 += __shfl_xor(a2, 16); a2 += __shfl_xor(a2, 32);
  b0 += __shfl_xor(b0, 16); b0 += __shfl_xor(b0, 32);
  b1 += __shfl_xor(b1, 16); b1 += __shfl_xor(b1, 32);
  b2 += __shfl_xor(b2, 16); b2 += __shfl_xor(b2, 32);
  if (g == 0) {
    size_t ro = (size_t)row * 16 + c;
    wsum[ro] = s0f[ro] + a0 + b0;
    m3h[ro] = __float2half(a1 + b1);
    m4h[ro] = __float2half(a2 + b2);
  }
}

// ---------------- final: logits = wsum + A1@m3 + A2@m4; softmax ----------------
__global__ __launch_bounds__(256) void final_spmm_softmax(
    const unsigned* __restrict__ srt1, const int* __restrict__ rp1,
    const unsigned* __restrict__ srt2, const int* __restrict__ rp2,
    const float* __restrict__ wsum, const __half* __restrict__ m3h,
    const __half* __restrict__ m4h, float* __restrict__ out, int n) {
  const int row = blockIdx.x * 4 + (threadIdx.x >> 6);
  if (row >= n) return;
  const int lane = threadIdx.x & 63;
  const int c = lane & 15, g = lane >> 4;
  float accA = 0.f, accB = 0.f;
  {
    const int j0 = rp1[row], j1 = rp1[row + 1];
    if (j1 > j0) {
      const int nit = (j1 - j0 + 15) >> 4;
      int j = j0 + g;
      for (int it = 0; it < nit; ++it, j += 16) {
        int jj0 = min(j, j1 - 1), jj1 = min(j + 4, j1 - 1);
        int jj2 = min(j + 8, j1 - 1), jj3 = min(j + 12, j1 - 1);
        unsigned e0 = __builtin_nontemporal_load(&srt1[jj0]);
        unsigned e1 = __builtin_nontemporal_load(&srt1[jj1]);
        unsigned e2 = __builtin_nontemporal_load(&srt1[jj2]);
        unsigned e3 = __builtin_nontemporal_load(&srt1[jj3]);
        float g0 = __half2float(m3h[(size_t)(e0 & 0xFFFF) * 16 + c]);
        float g1 = __half2float(m3h[(size_t)(e1 & 0xFFFF) * 16 + c]);
        float g2 = __half2float(m3h[(size_t)(e2 & 0xFFFF) * 16 + c]);
        float g3 = __half2float(m3h[(size_t)(e3 & 0xFFFF) * 16 + c]);
        float v0 = (j < j1) ? dec_val(e0) : 0.f;
        float v1 = (j + 4 < j1) ? dec_val(e1) : 0.f;
        float v2 = (j + 8 < j1) ? dec_val(e2) : 0.f;
        float v3 = (j + 12 < j1) ? dec_val(e3) : 0.f;
        accA += v0 * g0 + v1 * g1 + v2 * g2 + v3 * g3;
      }
    }
  }
  {
    const int j0 = rp2[row], j1 = rp2[row + 1];
    if (j1 > j0) {
      const int nit = (j1 - j0 + 15) >> 4;
      int j = j0 + g;
      for (int it = 0; it < nit; ++it, j += 16) {
        int jj0 = min(j, j1 - 1), jj1 = min(j + 4, j1 - 1);
        int jj2 = min(j + 8, j1 - 1), jj3 = min(j + 12, j1 - 1);
        unsigned e0 = __builtin_nontemporal_load(&srt2[jj0]);
        unsigned e1 = __builtin_nontemporal_load(&srt2[jj1]);
        unsigned e2 = __builtin_nontemporal_load(&srt2[jj2]);
        unsigned e3 = __builtin_nontemporal_load(&srt2[jj3]);
        float g0 = __half2float(m4h[(size_t)(e0 & 0xFFFF) * 16 + c]);
        float g1 = __half2float(m4h[(size_t)(e1 & 0xFFFF) * 16 + c]);
        float g2 = __half2float(m4h[(size_t)(e2 & 0xFFFF) * 16 + c]);
        float g3 = __half2float(m4h[(size_t)(e3 & 0xFFFF) * 16 + c]);
        float v0 = (j < j1) ? dec_val(e0) : 0.f;
        float v1 = (j + 4 < j1) ? dec_val(e1) : 0.f;
        float v2 = (j + 8 < j1) ? dec_val(e2) : 0.f;
        float v3 = (j + 12 < j1) ? dec_val(e3) : 0.f;
        accB += v0 * g0 + v1 * g1 + v2 * g2 + v3 * g3;
      }
    }
  }
  accA += __shfl_xor(accA, 16); accA += __shfl_xor(accA, 32);
  accB += __shfl_xor(accB, 16); accB += __shfl_xor(accB, 32);
  float logit = wsum[(size_t)row * 16 + c] + accA + accB;
  float m = logit;
#pragma unroll
  for (int off = 1; off < 16; off <<= 1) m = fmaxf(m, __shfl_xor(m, off));
  float e = __expf(logit - m);
  float s = e;
#pragma unroll
  for (int off = 1; off < 16; off <<= 1) s += __shfl_xor(s, off);
  float p = e / s;
  if (lane < 16) out[(size_t)row * NCLS + lane] = p;
}

extern "C" void kernel_launch(void* const* d_in, const int* in_sizes, int n_in,
                              void* d_out, int out_size, void* d_ws, size_t ws_size,
                              hipStream_t stream) {
  const float* x   = (const float*)d_in[0];
  const int*   a1r = (const int*)d_in[1];
  const int*   a1c = (const int*)d_in[2];
  const float* a1v = (const float*)d_in[3];
  const int*   a2r = (const int*)d_in[4];
  const int*   a2c = (const int*)d_in[5];
  const float* a2v = (const float*)d_in[6];
  const float* we  = (const float*)d_in[7];
  const float* wc  = (const float*)d_in[8];
  const int n  = in_sizes[0] / INF;   // 50000 (<= 65536 for 16-bit col pack)
  const int e1 = in_sizes[1];         // 1,000,000
  const int e2 = in_sizes[4];         // 1,500,000
  const int nbk = (n + BKW - 1) >> BKLG;   // 196 buckets of 256 rows

  // ---- workspace layout (~80 MB) ----
  char* w = (char*)d_ws;
  size_t off = 0;
  unsigned short* r0h = (unsigned short*)(w + off); off += (size_t)n * HID * 2;     // 12.8 MB
  unsigned short* r0l = (unsigned short*)(w + off); off += (size_t)n * HID * 2;     // 12.8 MB
  float* s0f  = (float*)(w + off); off += (size_t)n * 16 * 4;                       //  3.2 MB
  __half* Pa1 = (__half*)(w + off); off += (size_t)n * 64 * 2;                      //  6.4 MB
  __half* Pa2 = (__half*)(w + off); off += (size_t)n * 64 * 2;                      //  6.4 MB
  float* wsum = (float*)(w + off); off += (size_t)n * 16 * 4;                       //  3.2 MB
  __half* m3h = (__half*)(w + off); off += (size_t)n * 16 * 2;                      //  1.6 MB
  __half* m4h = (__half*)(w + off); off += (size_t)n * 16 * 2;                      //  1.6 MB
  int2* pack1 = (int2*)(w + off);  off += (size_t)e1 * 8;                           //  8 MB
  int2* pack2 = (int2*)(w + off);  off += (size_t)e2 * 8;                           // 12 MB
  unsigned* srt1 = (unsigned*)(w + off); off += (size_t)e1 * 4;                     //  4 MB
  unsigned* srt2 = (unsigned*)(w + off); off += (size_t)e2 * 4;                     //  6 MB
  unsigned short* wefh = (unsigned short*)(w + off); off += (size_t)512 * HID * 2;  // 128 KB
  unsigned short* wefl = (unsigned short*)(w + off); off += (size_t)512 * HID * 2;  // 128 KB
  unsigned short* wcfh = (unsigned short*)(w + off); off += (size_t)HID * PW * 2;   //  28 KB
  unsigned short* wcfl = (unsigned short*)(w + off); off += (size_t)HID * PW * 2;   //  28 KB
  int* g1 = (int*)(w + off); off += (size_t)512 * NB1 * 4;                          // 256 KB
  int* g2 = (int*)(w + off); off += (size_t)512 * NB2 * 4;                          // 384 KB
  int* rp1 = (int*)(w + off); off += (size_t)(n + 1) * 4;
  int* rp2 = (int*)(w + off); off += (size_t)(n + 1) * 4;
  int* bt1  = (int*)(w + off); off += (size_t)512 * 4;   // bucket totals (zeroed in prep_w)
  int* bt2  = (int*)(w + off); off += (size_t)512 * 4;
  int* ebt1 = (int*)(w + off); off += (size_t)512 * 4;   // exclusive bucket bases
  int* ebt2 = (int*)(w + off); off += (size_t)512 * 4;

  prep_w<<<312, 256, 0, stream>>>(we, wc, wefh, wefl, wcfh, wcfl, bt1);
  embed_mfma<<<(n + 63) / 64, 256, 0, stream>>>(x, wefh, wefl, r0h, r0l, n);
  proj_mfma<<<(n + 63) / 64, 256, 0, stream>>>(r0h, r0l, wcfh, wcfl, s0f, Pa1, Pa2, n);

  part_hist<<<dim3(NB2, 2), 256, 0, stream>>>(a1r, e1, a2r, e2, g1, g2, bt1, bt2, nbk);
  scan_bt<<<2, 256, 0, stream>>>(bt1, ebt1, bt2, ebt2, nbk);
  offs_scan<<<dim3(nbk, 2), 256, 0, stream>>>(g1, ebt1, g2, ebt2, nbk);
  part_scatter<<<dim3(NB2, 2), 256, 0, stream>>>(
      a1r, a1c, a1v, e1, a2r, a2c, a2v, e2, g1, g2, pack1, pack2, nbk);
  bucket_sort<<<dim3(nbk, 2), 256, 0, stream>>>(
      pack1, g1, srt1, rp1, e1, pack2, g2, srt2, rp2, e2, n, nbk);

  spmm48_both<<<(n + 3) / 4, 256, 0, stream>>>(
      srt1, rp1, srt2, rp2, Pa1, Pa2, s0f, wsum, m3h, m4h, n);
  final_spmm_softmax<<<(n + 3) / 4, 256, 0, stream>>>(
      srt1, rp1, srt2, rp2, wsum, m3h, m4h, (float*)d_out, n);
}

// Round 18
// 234.228 us; speedup vs baseline: 1.0978x; 1.0978x over previous
//
#include <hip/hip_runtime.h>
#include <hip/hip_fp16.h>

#define HID 128
#define INF 500
#define NCLS 16
#define PW  112    // projected width: [s0 | p1 q3a q4a | p2 q3b q4b]
#define BKLG 8
#define BKW 256    // rows per bucket
#define NB1 128    // partition blocks, matrix 1
#define NB2 192    // partition blocks, matrix 2

typedef __attribute__((ext_vector_type(8))) short short8v;
typedef __attribute__((ext_vector_type(4))) float f32x4;
typedef __attribute__((ext_vector_type(4))) float f4v;   // native vec for nontemporal builtins

// split fp32 into hi (truncated bf16) + lo (bf16 of remainder)
__device__ __forceinline__ void split_bf16(float v, unsigned short& h, unsigned short& l) {
  unsigned u = __float_as_uint(v);
  h = (unsigned short)(u >> 16);
  float hf = __uint_as_float(u & 0xFFFF0000u);
  l = (unsigned short)(__float_as_uint(v - hf) >> 16);
}

__device__ __forceinline__ void cvt8v(f4v c0, f4v c1, short8v& h8, short8v& l8) {
#pragma unroll
  for (int j = 0; j < 8; ++j) {
    float v = (j < 4) ? c0[j] : c1[j - 4];
    unsigned short h, l;
    split_bf16(v, h, l);
    h8[j] = (short)h;
    l8[j] = (short)l;
  }
}

// ---------------- weight prep (also zeroes bucket-total counters) ----------------
__global__ __launch_bounds__(256) void prep_w(
    const float* __restrict__ we, const float* __restrict__ wc,
    unsigned short* __restrict__ wh, unsigned short* __restrict__ wl,
    unsigned short* __restrict__ ch, unsigned short* __restrict__ cl,
    int* __restrict__ btz) {
  const int bid = blockIdx.x;
  if (bid == 0) {
    for (int i = threadIdx.x; i < 1024; i += 256) btz[i] = 0;
  }
  if (bid < 256) {
    int idx = bid * 256 + threadIdx.x;     // < 512*128
    int k = idx >> 7, nn = idx & 127;
    float v = (k < INF) ? we[k * HID + nn] : 0.f;
    unsigned short h, l;
    split_bf16(v, h, l);
    int kstep = k >> 5, ks = k & 31;
    int lane = (nn & 15) | ((ks >> 3) << 4);
    int j = ks & 7, nf = nn >> 4;
    size_t o = (((size_t)(kstep * 8 + nf)) * 64 + lane) * 8 + j;
    wh[o] = h;
    wl[o] = l;
  } else {
    int idx = (bid - 256) * 256 + threadIdx.x;
    if (idx >= HID * PW) return;
    int k = idx / PW, np = idx % PW;
    int o = np >> 4;
    int blk = (o == 0) ? 0 : ((o < 4) ? (2 * o - 1) : (2 * o - 6));
    float v = wc[(blk * HID + k) * NCLS + (np & 15)];
    unsigned short h, l;
    split_bf16(v, h, l);
    int kstep = k >> 5, ks = k & 31;
    int lane = (np & 15) | ((ks >> 3) << 4);
    int j = ks & 7, nf = np >> 4;
    size_t of = (((size_t)(kstep * 7 + nf)) * 64 + lane) * 8 + j;
    ch[of] = h;
    cl[of] = l;
  }
}

// ---------------- embed MFMA: r0 = relu(x @ we), bf16x3 ----------------
__global__ __launch_bounds__(128) void embed_mfma(
    const float* __restrict__ x, const unsigned short* __restrict__ wh,
    const unsigned short* __restrict__ wl, unsigned short* __restrict__ r0h,
    unsigned short* __restrict__ r0l, int n) {
  const int tid = threadIdx.x;
  const int wave = tid >> 6, lane = tid & 63;
  const int row0 = blockIdx.x * 64;
  const int rA = lane & 15, kg = lane >> 4;

  __shared__ float xs[64][68];   // 17.4 KB

  f32x4 acc[2][8];
#pragma unroll
  for (int rf = 0; rf < 2; ++rf)
#pragma unroll
    for (int nf = 0; nf < 8; ++nf)
#pragma unroll
      for (int r = 0; r < 4; ++r) acc[rf][nf][r] = 0.f;

  f4v pf[8];
#define LOAD_TILE(kt)                                                         \
  {                                                                           \
    const int k0_ = (kt) * 64;                                                \
    _Pragma("unroll")                                                         \
    for (int q = 0; q < 8; ++q) {                                             \
      int i_ = tid + q * 128;                                                 \
      int r_ = i_ >> 4, pos_ = i_ & 15;                                       \
      int gr_ = min(row0 + r_, n - 1);                                        \
      int gk_ = k0_ + pos_ * 4;                                               \
      pf[q] = (gk_ + 4 <= INF)                                                \
                  ? __builtin_nontemporal_load(                               \
                        (const f4v*)&x[(size_t)gr_ * INF + gk_])              \
                  : (f4v)(0.f);                                               \
    }                                                                         \
  }

  LOAD_TILE(0);
  for (int kt = 0; kt < 8; ++kt) {
#pragma unroll
    for (int q = 0; q < 8; ++q) {
      int i = tid + q * 128;
      *(f4v*)&xs[i >> 4][(i & 15) * 4] = pf[q];
    }
    __syncthreads();
    if (kt < 7) LOAD_TILE(kt + 1);

#pragma unroll
    for (int kh2 = 0; kh2 < 2; ++kh2) {
      const int kb = kh2 * 32 + kg * 8;
      short8v ah[2], al[2];
#pragma unroll
      for (int rf = 0; rf < 2; ++rf) {
        const int rl = wave * 32 + rf * 16 + rA;
        f4v c0 = *(const f4v*)&xs[rl][kb];
        f4v c1 = *(const f4v*)&xs[rl][kb + 4];
        cvt8v(c0, c1, ah[rf], al[rf]);
      }
      const size_t bbase = ((size_t)((kt * 2 + kh2) * 8) * 64 + lane) * 8;
      short8v Bh[8], Bl[8];
#pragma unroll
      for (int nf = 0; nf < 8; ++nf) {
        Bh[nf] = *(const short8v*)&wh[bbase + (size_t)nf * 512];
        Bl[nf] = *(const short8v*)&wl[bbase + (size_t)nf * 512];
      }
#pragma unroll
      for (int nf = 0; nf < 8; ++nf)
#pragma unroll
        for (int rf = 0; rf < 2; ++rf) {
          acc[rf][nf] = __builtin_amdgcn_mfma_f32_16x16x32_bf16(ah[rf], Bh[nf], acc[rf][nf], 0, 0, 0);
          acc[rf][nf] = __builtin_amdgcn_mfma_f32_16x16x32_bf16(ah[rf], Bl[nf], acc[rf][nf], 0, 0, 0);
          acc[rf][nf] = __builtin_amdgcn_mfma_f32_16x16x32_bf16(al[rf], Bh[nf], acc[rf][nf], 0, 0, 0);
        }
    }
    __syncthreads();
  }
#undef LOAD_TILE

#pragma unroll
  for (int rf = 0; rf < 2; ++rf)
#pragma unroll
    for (int nf = 0; nf < 8; ++nf) {
      const int row = row0 + wave * 32 + rf * 16 + kg * 4;
      const int col = nf * 16 + rA;
#pragma unroll
      for (int r = 0; r < 4; ++r) {
        if (row + r < n) {
          float v = fmaxf(acc[rf][nf][r], 0.f);
          unsigned short h, l;
          split_bf16(v, h, l);
          r0h[(size_t)(row + r) * HID + col] = h;
          r0l[(size_t)(row + r) * HID + col] = l;
        }
      }
    }
}

// ---------------- proj MFMA: [s0|Pa1|Pa2] = r0 @ wcP, bf16x3, 4 waves x 16 rows ----------------
__global__ __launch_bounds__(256) void proj_mfma(
    const unsigned short* __restrict__ r0h, const unsigned short* __restrict__ r0l,
    const unsigned short* __restrict__ ch, const unsigned short* __restrict__ cl,
    float* __restrict__ s0f, __half* __restrict__ Pa1, __half* __restrict__ Pa2, int n) {
  const int wave = threadIdx.x >> 6, lane = threadIdx.x & 63;
  const int row0 = blockIdx.x * 64 + wave * 16;
  const int rA = lane & 15, kg = lane >> 4;

  f32x4 acc[7];
#pragma unroll
  for (int nf = 0; nf < 7; ++nf)
#pragma unroll
    for (int r = 0; r < 4; ++r) acc[nf][r] = 0.f;

  const unsigned short* arh = &r0h[(size_t)min(row0 + rA, n - 1) * HID];
  const unsigned short* arl = &r0l[(size_t)min(row0 + rA, n - 1) * HID];

#pragma unroll
  for (int kstep = 0; kstep < 4; ++kstep) {
    const int kb = kstep * 32 + kg * 8;
    short8v ah = __builtin_nontemporal_load((const short8v*)&arh[kb]);
    short8v al = __builtin_nontemporal_load((const short8v*)&arl[kb]);

    const size_t bbase = ((size_t)kstep * 7 * 64 + lane) * 8;
    short8v Bh[7], Bl[7];
#pragma unroll
    for (int nf = 0; nf < 7; ++nf) {
      Bh[nf] = *(const short8v*)&ch[bbase + (size_t)nf * 512];
      Bl[nf] = *(const short8v*)&cl[bbase + (size_t)nf * 512];
    }
#pragma unroll
    for (int nf = 0; nf < 7; ++nf) {
      acc[nf] = __builtin_amdgcn_mfma_f32_16x16x32_bf16(ah, Bh[nf], acc[nf], 0, 0, 0);
      acc[nf] = __builtin_amdgcn_mfma_f32_16x16x32_bf16(ah, Bl[nf], acc[nf], 0, 0, 0);
      acc[nf] = __builtin_amdgcn_mfma_f32_16x16x32_bf16(al, Bh[nf], acc[nf], 0, 0, 0);
    }
  }

#pragma unroll
  for (int nf = 0; nf < 7; ++nf) {
    const int row = row0 + kg * 4;
#pragma unroll
    for (int r = 0; r < 4; ++r) {
      if (row + r < n) {
        float v = acc[nf][r];
        size_t ro = (size_t)(row + r) * 16 + rA;
        if (nf == 0) {
          s0f[ro] = v;
        } else if (nf < 4) {
          Pa1[ro * 4 + (nf - 1)] = __float2half(v);
          if (nf == 1) Pa1[ro * 4 + 3] = __float2half(0.f);
        } else {
          Pa2[ro * 4 + (nf - 4)] = __float2half(v);
          if (nf == 4) Pa2[ro * 4 + 3] = __float2half(0.f);
        }
      }
    }
  }
}

// ---------------- radix partition ----------------
__global__ __launch_bounds__(256) void part_hist(
    const int* __restrict__ r1, int e1, const int* __restrict__ r2, int e2,
    int* __restrict__ g1, int* __restrict__ g2,
    int* __restrict__ bt1, int* __restrict__ bt2, int nbk) {
  const int m = blockIdx.y;
  const int NB = m ? NB2 : NB1;
  const int b = blockIdx.x;
  if (b >= NB) return;
  const int* rows = m ? r2 : r1;
  const int E = m ? e2 : e1;
  int* g = m ? g2 : g1;
  int* bt = m ? bt2 : bt1;
  __shared__ int h[512];
  for (int i = threadIdx.x; i < nbk; i += 256) h[i] = 0;
  __syncthreads();
  const int ch = (E + NB - 1) / NB;
  const int lo = b * ch, hi = min(lo + ch, E);
  for (int i = lo + threadIdx.x; i < hi; i += 256)
    atomicAdd(&h[rows[i] >> BKLG], 1);
  __syncthreads();
  for (int k = threadIdx.x; k < nbk; k += 256) {
    g[(size_t)k * NB + b] = h[k];
    if (h[k]) atomicAdd(&bt[k], h[k]);
  }
}

// scan bucket totals -> exclusive bucket bases (1 block per matrix)
__global__ __launch_bounds__(256) void scan_bt(
    const int* __restrict__ bt1, int* __restrict__ ebt1,
    const int* __restrict__ bt2, int* __restrict__ ebt2, int nbk) {
  const int* bt = blockIdx.x ? bt2 : bt1;
  int* ebt = blockIdx.x ? ebt2 : ebt1;
  __shared__ int sh[256];
  const int t = threadIdx.x;
  int v = (t < nbk) ? bt[t] : 0;
  sh[t] = v;
  __syncthreads();
  for (int d = 1; d < 256; d <<= 1) {
    int u = (t >= d) ? sh[t - d] : 0;
    __syncthreads();
    sh[t] += u;
    __syncthreads();
  }
  if (t < nbk) ebt[t] = sh[t] - v;
}

// per-bucket scan of per-block counts -> global offsets (parallel over buckets)
__global__ __launch_bounds__(256) void offs_scan(
    int* __restrict__ g1, const int* __restrict__ ebt1,
    int* __restrict__ g2, const int* __restrict__ ebt2, int nbk) {
  const int m = blockIdx.y;
  const int NB = m ? NB2 : NB1;
  int* g = m ? g2 : g1;
  const int* ebt = m ? ebt2 : ebt1;
  const int k = blockIdx.x;
  __shared__ int sh[256];
  const int t = threadIdx.x;
  int v = (t < NB) ? g[(size_t)k * NB + t] : 0;
  sh[t] = v;
  __syncthreads();
  for (int d = 1; d < 256; d <<= 1) {
    int u = (t >= d) ? sh[t - d] : 0;
    __syncthreads();
    sh[t] += u;
    __syncthreads();
  }
  if (t < NB) g[(size_t)k * NB + t] = ebt[k] + sh[t] - v;
}

// scatter: block b's writes to bucket k form one contiguous run (write-amp ~1x)
__global__ __launch_bounds__(256) void part_scatter(
    const int* __restrict__ r1, const int* __restrict__ c1, const float* __restrict__ v1, int e1,
    const int* __restrict__ r2, const int* __restrict__ c2, const float* __restrict__ v2, int e2,
    const int* __restrict__ g1, const int* __restrict__ g2,
    int2* __restrict__ pack1, int2* __restrict__ pack2, int nbk) {
  const int m = blockIdx.y;
  const int NB = m ? NB2 : NB1;
  const int b = blockIdx.x;
  if (b >= NB) return;
  const int* rows = m ? r2 : r1;
  const int* cols = m ? c2 : c1;
  const float* vals = m ? v2 : v1;
  const int E = m ? e2 : e1;
  const int* g = m ? g2 : g1;
  int2* pack = m ? pack2 : pack1;
  __shared__ int lcur[512];
  for (int k = threadIdx.x; k < nbk; k += 256) lcur[k] = g[(size_t)k * NB + b];
  __syncthreads();
  const int ch = (E + NB - 1) / NB;
  const int lo = b * ch, hi = min(lo + ch, E);
  for (int i = lo + threadIdx.x; i < hi; i += 256) {
    int r = rows[i];
    int pos = atomicAdd(&lcur[r >> BKLG], 1);
    unsigned u = (unsigned)(vals[i] * 65536.0f);
    if (u > 65535u) u = 65535u;
    pack[pos] = make_int2(cols[i] | ((r & (BKW - 1)) << 16), (int)u);
  }
}

// per-bucket LDS counting sort (256 rows) -> row-sorted 4B edges + per-row rp
__global__ __launch_bounds__(256) void bucket_sort(
    const int2* __restrict__ pack1, const int* __restrict__ g1,
    unsigned* __restrict__ srt1, int* __restrict__ rp1, int e1,
    const int2* __restrict__ pack2, const int* __restrict__ g2,
    unsigned* __restrict__ srt2, int* __restrict__ rp2, int e2,
    int n, int nbk) {
  const int m = blockIdx.y;
  const int NB = m ? NB2 : NB1;
  const int2* pack = m ? pack2 : pack1;
  const int* g = m ? g2 : g1;
  unsigned* srt = m ? srt2 : srt1;
  int* rp = m ? rp2 : rp1;
  const int E = m ? e2 : e1;
  const int k = blockIdx.x;
  const int base = g[(size_t)k * NB];
  const int end = (k + 1 < nbk) ? g[(size_t)(k + 1) * NB] : E;
  __shared__ int lcnt[256], lws[256], lcur[256];
  const int t = threadIdx.x;
  lcnt[t] = 0;
  __syncthreads();
  // count pass: only the .x word is needed (half the bytes of full int2 loads)
  const int* packx = (const int*)pack;
  for (int i = base + t; i < end; i += 256)
    atomicAdd(&lcnt[(packx[2 * i] >> 16) & (BKW - 1)], 1);
  __syncthreads();
  int s = lcnt[t];
  lws[t] = s;
  __syncthreads();
  for (int d = 1; d < 256; d <<= 1) {
    int v = (t >= d) ? lws[t - d] : 0;
    __syncthreads();
    lws[t] += v;
    __syncthreads();
  }
  int excl = base + lws[t] - s;
  lcur[t] = excl;
  int row = k * BKW + t;
  if (row < n) rp[row] = excl;
  if (k == nbk - 1 && t == 0) rp[n] = E;
  __syncthreads();
  for (int i = base + t; i < end; i += 256) {
    int2 e = pack[i];
    int pos = atomicAdd(&lcur[(e.x >> 16) & (BKW - 1)], 1);
    srt[pos] = (unsigned)(e.x & 0xFFFF) | ((unsigned)e.y << 16);
  }
}

__device__ __forceinline__ float dec_val(unsigned e) {
  return ((float)(e >> 16) + 0.5f) * (1.0f / 65536.0f);
}

// ---------------- fused SpMM (both matrices, 48-wide) + combine ----------------
__global__ __launch_bounds__(256) void spmm48_both(
    const unsigned* __restrict__ srt1, const int* __restrict__ rp1,
    const unsigned* __restrict__ srt2, const int* __restrict__ rp2,
    const __half* __restrict__ Pa1, const __half* __restrict__ Pa2,
    const float* __restrict__ s0f, float* __restrict__ wsum,
    __half* __restrict__ m3h, __half* __restrict__ m4h, int n) {
  const int row = blockIdx.x * 4 + (threadIdx.x >> 6);
  if (row >= n) return;
  const int lane = threadIdx.x & 63;
  const int c = lane & 15, g = lane >> 4;
  float a0 = 0.f, a1 = 0.f, a2 = 0.f, b0 = 0.f, b1 = 0.f, b2 = 0.f;
  {
    const int j0 = rp1[row], j1 = rp1[row + 1];
    if (j1 > j0) {
      const int nit = (j1 - j0 + 15) >> 4;
      int j = j0 + g;
      for (int it = 0; it < nit; ++it, j += 16) {
        int jj0 = min(j, j1 - 1), jj1 = min(j + 4, j1 - 1);
        int jj2 = min(j + 8, j1 - 1), jj3 = min(j + 12, j1 - 1);
        unsigned e0 = __builtin_nontemporal_load(&srt1[jj0]);
        unsigned e1 = __builtin_nontemporal_load(&srt1[jj1]);
        unsigned e2 = __builtin_nontemporal_load(&srt1[jj2]);
        unsigned e3 = __builtin_nontemporal_load(&srt1[jj3]);
        float2 r0 = *(const float2*)(Pa1 + ((size_t)(e0 & 0xFFFF) * 16 + c) * 4);
        float2 r1 = *(const float2*)(Pa1 + ((size_t)(e1 & 0xFFFF) * 16 + c) * 4);
        float2 r2 = *(const float2*)(Pa1 + ((size_t)(e2 & 0xFFFF) * 16 + c) * 4);
        float2 r3 = *(const float2*)(Pa1 + ((size_t)(e3 & 0xFFFF) * 16 + c) * 4);
        float v0 = (j < j1) ? dec_val(e0) : 0.f;
        float v1 = (j + 4 < j1) ? dec_val(e1) : 0.f;
        float v2 = (j + 8 < j1) ? dec_val(e2) : 0.f;
        float v3 = (j + 12 < j1) ? dec_val(e3) : 0.f;
        float2 f00 = __half22float2(*(__half2*)&r0.x), f01 = __half22float2(*(__half2*)&r0.y);
        float2 f10 = __half22float2(*(__half2*)&r1.x), f11 = __half22float2(*(__half2*)&r1.y);
        float2 f20 = __half22float2(*(__half2*)&r2.x), f21 = __half22float2(*(__half2*)&r2.y);
        float2 f30 = __half22float2(*(__half2*)&r3.x), f31 = __half22float2(*(__half2*)&r3.y);
        a0 += v0 * f00.x + v1 * f10.x + v2 * f20.x + v3 * f30.x;
        a1 += v0 * f00.y + v1 * f10.y + v2 * f20.y + v3 * f30.y;
        a2 += v0 * f01.x + v1 * f11.x + v2 * f21.x + v3 * f31.x;
      }
    }
  }
  {
    const int j0 = rp2[row], j1 = rp2[row + 1];
    if (j1 > j0) {
      const int nit = (j1 - j0 + 15) >> 4;
      int j = j0 + g;
      for (int it = 0; it < nit; ++it, j += 16) {
        int jj0 = min(j, j1 - 1), jj1 = min(j + 4, j1 - 1);
        int jj2 = min(j + 8, j1 - 1), jj3 = min(j + 12, j1 - 1);
        unsigned e0 = __builtin_nontemporal_load(&srt2[jj0]);
        unsigned e1 = __builtin_nontemporal_load(&srt2[jj1]);
        unsigned e2 = __builtin_nontemporal_load(&srt2[jj2]);
        unsigned e3 = __builtin_nontemporal_load(&srt2[jj3]);
        float2 r0 = *(const float2*)(Pa2 + ((size_t)(e0 & 0xFFFF) * 16 + c) * 4);
        float2 r1 = *(const float2*)(Pa2 + ((size_t)(e1 & 0xFFFF) * 16 + c) * 4);
        float2 r2 = *(const float2*)(Pa2 + ((size_t)(e2 & 0xFFFF) * 16 + c) * 4);
        float2 r3 = *(const float2*)(Pa2 + ((size_t)(e3 & 0xFFFF) * 16 + c) * 4);
        float v0 = (j < j1) ? dec_val(e0) : 0.f;
        float v1 = (j + 4 < j1) ? dec_val(e1) : 0.f;
        float v2 = (j + 8 < j1) ? dec_val(e2) : 0.f;
        float v3 = (j + 12 < j1) ? dec_val(e3) : 0.f;
        float2 f00 = __half22float2(*(__half2*)&r0.x), f01 = __half22float2(*(__half2*)&r0.y);
        float2 f10 = __half22float2(*(__half2*)&r1.x), f11 = __half22float2(*(__half2*)&r1.y);
        float2 f20 = __half22float2(*(__half2*)&r2.x), f21 = __half22float2(*(__half2*)&r2.y);
        float2 f30 = __half22float2(*(__half2*)&r3.x), f31 = __half22float2(*(__half2*)&r3.y);
        b0 += v0 * f00.x + v1 * f10.x + v2 * f20.x + v3 * f30.x;
        b1 += v0 * f00.y + v1 * f10.y + v2 * f20.y + v3 * f30.y;
        b2 += v0 * f01.x + v1 * f11.x + v2 * f21.x + v3 * f31.x;
      }
    }
  }
  a0 += __shfl_xor(a0, 16); a0 += __shfl_xor(a0, 32);
  a1 += __shfl_xor(a1, 16); a1 += __shfl_xor(a1, 32);
  a2 += __shfl_xor(a2, 16); a2 += __shfl_xor(a2, 32);
  b0 += __shfl_xor(b0, 16); b0 += __shfl_xor(b0, 32);
  b1 += __shfl_xor(b1, 16); b1 += __shfl_xor(b1, 32);
  b2 += __shfl_xor(b2, 16); b2 += __shfl_xor(b2, 32);
  if (g == 0) {
    size_t ro = (size_t)row * 16 + c;
    wsum[ro] = s0f[ro] + a0 + b0;
    m3h[ro] = __float2half(a1 + b1);
    m4h[ro] = __float2half(a2 + b2);
  }
}

// ---------------- final: logits = wsum + A1@m3 + A2@m4; softmax ----------------
__global__ __launch_bounds__(256) void final_spmm_softmax(
    const unsigned* __restrict__ srt1, const int* __restrict__ rp1,
    const unsigned* __restrict__ srt2, const int* __restrict__ rp2,
    const float* __restrict__ wsum, const __half* __restrict__ m3h,
    const __half* __restrict__ m4h, float* __restrict__ out, int n) {
  const int row = blockIdx.x * 4 + (threadIdx.x >> 6);
  if (row >= n) return;
  const int lane = threadIdx.x & 63;
  const int c = lane & 15, g = lane >> 4;
  float accA = 0.f, accB = 0.f;
  {
    const int j0 = rp1[row], j1 = rp1[row + 1];
    if (j1 > j0) {
      const int nit = (j1 - j0 + 15) >> 4;
      int j = j0 + g;
      for (int it = 0; it < nit; ++it, j += 16) {
        int jj0 = min(j, j1 - 1), jj1 = min(j + 4, j1 - 1);
        int jj2 = min(j + 8, j1 - 1), jj3 = min(j + 12, j1 - 1);
        unsigned e0 = __builtin_nontemporal_load(&srt1[jj0]);
        unsigned e1 = __builtin_nontemporal_load(&srt1[jj1]);
        unsigned e2 = __builtin_nontemporal_load(&srt1[jj2]);
        unsigned e3 = __builtin_nontemporal_load(&srt1[jj3]);
        float g0 = __half2float(m3h[(size_t)(e0 & 0xFFFF) * 16 + c]);
        float g1 = __half2float(m3h[(size_t)(e1 & 0xFFFF) * 16 + c]);
        float g2 = __half2float(m3h[(size_t)(e2 & 0xFFFF) * 16 + c]);
        float g3 = __half2float(m3h[(size_t)(e3 & 0xFFFF) * 16 + c]);
        float v0 = (j < j1) ? dec_val(e0) : 0.f;
        float v1 = (j + 4 < j1) ? dec_val(e1) : 0.f;
        float v2 = (j + 8 < j1) ? dec_val(e2) : 0.f;
        float v3 = (j + 12 < j1) ? dec_val(e3) : 0.f;
        accA += v0 * g0 + v1 * g1 + v2 * g2 + v3 * g3;
      }
    }
  }
  {
    const int j0 = rp2[row], j1 = rp2[row + 1];
    if (j1 > j0) {
      const int nit = (j1 - j0 + 15) >> 4;
      int j = j0 + g;
      for (int it = 0; it < nit; ++it, j += 16) {
        int jj0 = min(j, j1 - 1), jj1 = min(j + 4, j1 - 1);
        int jj2 = min(j + 8, j1 - 1), jj3 = min(j + 12, j1 - 1);
        unsigned e0 = __builtin_nontemporal_load(&srt2[jj0]);
        unsigned e1 = __builtin_nontemporal_load(&srt2[jj1]);
        unsigned e2 = __builtin_nontemporal_load(&srt2[jj2]);
        unsigned e3 = __builtin_nontemporal_load(&srt2[jj3]);
        float g0 = __half2float(m4h[(size_t)(e0 & 0xFFFF) * 16 + c]);
        float g1 = __half2float(m4h[(size_t)(e1 & 0xFFFF) * 16 + c]);
        float g2 = __half2float(m4h[(size_t)(e2 & 0xFFFF) * 16 + c]);
        float g3 = __half2float(m4h[(size_t)(e3 & 0xFFFF) * 16 + c]);
        float v0 = (j < j1) ? dec_val(e0) : 0.f;
        float v1 = (j + 4 < j1) ? dec_val(e1) : 0.f;
        float v2 = (j + 8 < j1) ? dec_val(e2) : 0.f;
        float v3 = (j + 12 < j1) ? dec_val(e3) : 0.f;
        accB += v0 * g0 + v1 * g1 + v2 * g2 + v3 * g3;
      }
    }
  }
  accA += __shfl_xor(accA, 16); accA += __shfl_xor(accA, 32);
  accB += __shfl_xor(accB, 16); accB += __shfl_xor(accB, 32);
  float logit = wsum[(size_t)row * 16 + c] + accA + accB;
  float m = logit;
#pragma unroll
  for (int off = 1; off < 16; off <<= 1) m = fmaxf(m, __shfl_xor(m, off));
  float e = __expf(logit - m);
  float s = e;
#pragma unroll
  for (int off = 1; off < 16; off <<= 1) s += __shfl_xor(s, off);
  float p = e / s;
  if (lane < 16) out[(size_t)row * NCLS + lane] = p;
}

extern "C" void kernel_launch(void* const* d_in, const int* in_sizes, int n_in,
                              void* d_out, int out_size, void* d_ws, size_t ws_size,
                              hipStream_t stream) {
  const float* x   = (const float*)d_in[0];
  const int*   a1r = (const int*)d_in[1];
  const int*   a1c = (const int*)d_in[2];
  const float* a1v = (const float*)d_in[3];
  const int*   a2r = (const int*)d_in[4];
  const int*   a2c = (const int*)d_in[5];
  const float* a2v = (const float*)d_in[6];
  const float* we  = (const float*)d_in[7];
  const float* wc  = (const float*)d_in[8];
  const int n  = in_sizes[0] / INF;   // 50000 (<= 65536 for 16-bit col pack)
  const int e1 = in_sizes[1];         // 1,000,000
  const int e2 = in_sizes[4];         // 1,500,000
  const int nbk = (n + BKW - 1) >> BKLG;   // 196 buckets of 256 rows

  // ---- workspace layout (~80 MB) ----
  char* w = (char*)d_ws;
  size_t off = 0;
  unsigned short* r0h = (unsigned short*)(w + off); off += (size_t)n * HID * 2;     // 12.8 MB
  unsigned short* r0l = (unsigned short*)(w + off); off += (size_t)n * HID * 2;     // 12.8 MB
  float* s0f  = (float*)(w + off); off += (size_t)n * 16 * 4;                       //  3.2 MB
  __half* Pa1 = (__half*)(w + off); off += (size_t)n * 64 * 2;                      //  6.4 MB
  __half* Pa2 = (__half*)(w + off); off += (size_t)n * 64 * 2;                      //  6.4 MB
  float* wsum = (float*)(w + off); off += (size_t)n * 16 * 4;                       //  3.2 MB
  __half* m3h = (__half*)(w + off); off += (size_t)n * 16 * 2;                      //  1.6 MB
  __half* m4h = (__half*)(w + off); off += (size_t)n * 16 * 2;                      //  1.6 MB
  int2* pack1 = (int2*)(w + off);  off += (size_t)e1 * 8;                           //  8 MB
  int2* pack2 = (int2*)(w + off);  off += (size_t)e2 * 8;                           // 12 MB
  unsigned* srt1 = (unsigned*)(w + off); off += (size_t)e1 * 4;                     //  4 MB
  unsigned* srt2 = (unsigned*)(w + off); off += (size_t)e2 * 4;                     //  6 MB
  unsigned short* wefh = (unsigned short*)(w + off); off += (size_t)512 * HID * 2;  // 128 KB
  unsigned short* wefl = (unsigned short*)(w + off); off += (size_t)512 * HID * 2;  // 128 KB
  unsigned short* wcfh = (unsigned short*)(w + off); off += (size_t)HID * PW * 2;   //  28 KB
  unsigned short* wcfl = (unsigned short*)(w + off); off += (size_t)HID * PW * 2;   //  28 KB
  int* g1 = (int*)(w + off); off += (size_t)512 * NB1 * 4;                          // 256 KB
  int* g2 = (int*)(w + off); off += (size_t)512 * NB2 * 4;                          // 384 KB
  int* rp1 = (int*)(w + off); off += (size_t)(n + 1) * 4;
  int* rp2 = (int*)(w + off); off += (size_t)(n + 1) * 4;
  int* bt1  = (int*)(w + off); off += (size_t)512 * 4;   // bucket totals (zeroed in prep_w)
  int* bt2  = (int*)(w + off); off += (size_t)512 * 4;
  int* ebt1 = (int*)(w + off); off += (size_t)512 * 4;   // exclusive bucket bases
  int* ebt2 = (int*)(w + off); off += (size_t)512 * 4;

  prep_w<<<312, 256, 0, stream>>>(we, wc, wefh, wefl, wcfh, wcfl, bt1);
  embed_mfma<<<(n + 63) / 64, 128, 0, stream>>>(x, wefh, wefl, r0h, r0l, n);
  proj_mfma<<<(n + 63) / 64, 256, 0, stream>>>(r0h, r0l, wcfh, wcfl, s0f, Pa1, Pa2, n);

  part_hist<<<dim3(NB2, 2), 256, 0, stream>>>(a1r, e1, a2r, e2, g1, g2, bt1, bt2, nbk);
  scan_bt<<<2, 256, 0, stream>>>(bt1, ebt1, bt2, ebt2, nbk);
  offs_scan<<<dim3(nbk, 2), 256, 0, stream>>>(g1, ebt1, g2, ebt2, nbk);
  part_scatter<<<dim3(NB2, 2), 256, 0, stream>>>(
      a1r, a1c, a1v, e1, a2r, a2c, a2v, e2, g1, g2, pack1, pack2, nbk);
  bucket_sort<<<dim3(nbk, 2), 256, 0, stream>>>(
      pack1, g1, srt1, rp1, e1, pack2, g2, srt2, rp2, e2, n, nbk);

  spmm48_both<<<(n + 3) / 4, 256, 0, stream>>>(
      srt1, rp1, srt2, rp2, Pa1, Pa2, s0f, wsum, m3h, m4h, n);
  final_spmm_softmax<<<(n + 3) / 4, 256, 0, stream>>>(
      srt1, rp1, srt2, rp2, wsum, m3h, m4h, (float*)d_out, n);
}

// Round 19
// 230.166 us; speedup vs baseline: 1.1172x; 1.0176x over previous
//
#include <hip/hip_runtime.h>
#include <hip/hip_fp16.h>

#define HID 128
#define INF 500
#define NCLS 16
#define PW  112    // projected width: [s0 | p1 q3a q4a | p2 q3b q4b]
#define BKLG 8
#define BKW 256    // rows per bucket
#define NB1 128    // partition blocks, matrix 1
#define NB2 192    // partition blocks, matrix 2

typedef __attribute__((ext_vector_type(8))) short short8v;
typedef __attribute__((ext_vector_type(4))) float f32x4;
typedef __attribute__((ext_vector_type(4))) float f4v;   // native vec for nontemporal builtins

// split fp32 into hi (truncated bf16) + lo (bf16 of remainder)
__device__ __forceinline__ void split_bf16(float v, unsigned short& h, unsigned short& l) {
  unsigned u = __float_as_uint(v);
  h = (unsigned short)(u >> 16);
  float hf = __uint_as_float(u & 0xFFFF0000u);
  l = (unsigned short)(__float_as_uint(v - hf) >> 16);
}

__device__ __forceinline__ void cvt8v(f4v c0, f4v c1, short8v& h8, short8v& l8) {
#pragma unroll
  for (int j = 0; j < 8; ++j) {
    float v = (j < 4) ? c0[j] : c1[j - 4];
    unsigned short h, l;
    split_bf16(v, h, l);
    h8[j] = (short)h;
    l8[j] = (short)l;
  }
}

// ---------------- weight prep (also zeroes bucket-total counters) ----------------
__global__ __launch_bounds__(256) void prep_w(
    const float* __restrict__ we, const float* __restrict__ wc,
    unsigned short* __restrict__ wh, unsigned short* __restrict__ wl,
    unsigned short* __restrict__ ch, unsigned short* __restrict__ cl,
    int* __restrict__ btz) {
  const int bid = blockIdx.x;
  if (bid == 0) {
    for (int i = threadIdx.x; i < 1024; i += 256) btz[i] = 0;
  }
  if (bid < 256) {
    int idx = bid * 256 + threadIdx.x;     // < 512*128
    int k = idx >> 7, nn = idx & 127;
    float v = (k < INF) ? we[k * HID + nn] : 0.f;
    unsigned short h, l;
    split_bf16(v, h, l);
    int kstep = k >> 5, ks = k & 31;
    int lane = (nn & 15) | ((ks >> 3) << 4);
    int j = ks & 7, nf = nn >> 4;
    size_t o = (((size_t)(kstep * 8 + nf)) * 64 + lane) * 8 + j;
    wh[o] = h;
    wl[o] = l;
  } else {
    int idx = (bid - 256) * 256 + threadIdx.x;
    if (idx >= HID * PW) return;
    int k = idx / PW, np = idx % PW;
    int o = np >> 4;
    int blk = (o == 0) ? 0 : ((o < 4) ? (2 * o - 1) : (2 * o - 6));
    float v = wc[(blk * HID + k) * NCLS + (np & 15)];
    unsigned short h, l;
    split_bf16(v, h, l);
    int kstep = k >> 5, ks = k & 31;
    int lane = (np & 15) | ((ks >> 3) << 4);
    int j = ks & 7, nf = np >> 4;
    size_t of = (((size_t)(kstep * 7 + nf)) * 64 + lane) * 8 + j;
    ch[of] = h;
    cl[of] = l;
  }
}

// ---------------- embed MFMA: r0 = relu(x @ we), bf16x3 ----------------
// 128 rows/block, 256 threads = 4 waves x 32 rows (same per-wave structure as the
// proven 2-wave version; 4-way B-line sharing within block halves global B traffic).
__global__ __launch_bounds__(256) void embed_mfma(
    const float* __restrict__ x, const unsigned short* __restrict__ wh,
    const unsigned short* __restrict__ wl, unsigned short* __restrict__ r0h,
    unsigned short* __restrict__ r0l, int n) {
  const int tid = threadIdx.x;
  const int wave = tid >> 6, lane = tid & 63;
  const int row0 = blockIdx.x * 128;
  const int rA = lane & 15, kg = lane >> 4;

  __shared__ float xs[128][68];   // 34.8 KB

  f32x4 acc[2][8];
#pragma unroll
  for (int rf = 0; rf < 2; ++rf)
#pragma unroll
    for (int nf = 0; nf < 8; ++nf)
#pragma unroll
      for (int r = 0; r < 4; ++r) acc[rf][nf][r] = 0.f;

  f4v pf[8];
  // tile: 128 rows x 64 k; slot i = tid + q*256 -> row i>>4, pos i&15 (coalesced)
#define LOAD_TILE(kt)                                                         \
  {                                                                           \
    const int k0_ = (kt) * 64;                                                \
    _Pragma("unroll")                                                         \
    for (int q = 0; q < 8; ++q) {                                             \
      int i_ = tid + q * 256;                                                 \
      int r_ = i_ >> 4, pos_ = i_ & 15;                                       \
      int gr_ = min(row0 + r_, n - 1);                                        \
      int gk_ = k0_ + pos_ * 4;                                               \
      pf[q] = (gk_ + 4 <= INF)                                                \
                  ? __builtin_nontemporal_load(                               \
                        (const f4v*)&x[(size_t)gr_ * INF + gk_])              \
                  : (f4v)(0.f);                                               \
    }                                                                         \
  }

  LOAD_TILE(0);
  for (int kt = 0; kt < 8; ++kt) {
#pragma unroll
    for (int q = 0; q < 8; ++q) {
      int i = tid + q * 256;
      *(f4v*)&xs[i >> 4][(i & 15) * 4] = pf[q];
    }
    __syncthreads();
    if (kt < 7) LOAD_TILE(kt + 1);   // next-tile loads in flight under compute

#pragma unroll
    for (int kh2 = 0; kh2 < 2; ++kh2) {
      const int kb = kh2 * 32 + kg * 8;
      short8v ah[2], al[2];
#pragma unroll
      for (int rf = 0; rf < 2; ++rf) {
        const int rl = wave * 32 + rf * 16 + rA;
        f4v c0 = *(const f4v*)&xs[rl][kb];
        f4v c1 = *(const f4v*)&xs[rl][kb + 4];
        cvt8v(c0, c1, ah[rf], al[rf]);
      }
      const size_t bbase = ((size_t)((kt * 2 + kh2) * 8) * 64 + lane) * 8;
      short8v Bh[8], Bl[8];
#pragma unroll
      for (int nf = 0; nf < 8; ++nf) {
        Bh[nf] = *(const short8v*)&wh[bbase + (size_t)nf * 512];
        Bl[nf] = *(const short8v*)&wl[bbase + (size_t)nf * 512];
      }
#pragma unroll
      for (int nf = 0; nf < 8; ++nf)
#pragma unroll
        for (int rf = 0; rf < 2; ++rf) {
          acc[rf][nf] = __builtin_amdgcn_mfma_f32_16x16x32_bf16(ah[rf], Bh[nf], acc[rf][nf], 0, 0, 0);
          acc[rf][nf] = __builtin_amdgcn_mfma_f32_16x16x32_bf16(ah[rf], Bl[nf], acc[rf][nf], 0, 0, 0);
          acc[rf][nf] = __builtin_amdgcn_mfma_f32_16x16x32_bf16(al[rf], Bh[nf], acc[rf][nf], 0, 0, 0);
        }
    }
    __syncthreads();
  }
#undef LOAD_TILE

#pragma unroll
  for (int rf = 0; rf < 2; ++rf)
#pragma unroll
    for (int nf = 0; nf < 8; ++nf) {
      const int row = row0 + wave * 32 + rf * 16 + kg * 4;
      const int col = nf * 16 + rA;
#pragma unroll
      for (int r = 0; r < 4; ++r) {
        if (row + r < n) {
          float v = fmaxf(acc[rf][nf][r], 0.f);
          unsigned short h, l;
          split_bf16(v, h, l);
          r0h[(size_t)(row + r) * HID + col] = h;
          r0l[(size_t)(row + r) * HID + col] = l;
        }
      }
    }
}

// ---------------- proj MFMA: [s0|Pa1|Pa2] = r0 @ wcP, bf16x3, 4 waves x 16 rows ----------------
__global__ __launch_bounds__(256) void proj_mfma(
    const unsigned short* __restrict__ r0h, const unsigned short* __restrict__ r0l,
    const unsigned short* __restrict__ ch, const unsigned short* __restrict__ cl,
    float* __restrict__ s0f, __half* __restrict__ Pa1, __half* __restrict__ Pa2, int n) {
  const int wave = threadIdx.x >> 6, lane = threadIdx.x & 63;
  const int row0 = blockIdx.x * 64 + wave * 16;
  const int rA = lane & 15, kg = lane >> 4;

  f32x4 acc[7];
#pragma unroll
  for (int nf = 0; nf < 7; ++nf)
#pragma unroll
    for (int r = 0; r < 4; ++r) acc[nf][r] = 0.f;

  const unsigned short* arh = &r0h[(size_t)min(row0 + rA, n - 1) * HID];
  const unsigned short* arl = &r0l[(size_t)min(row0 + rA, n - 1) * HID];

#pragma unroll
  for (int kstep = 0; kstep < 4; ++kstep) {
    const int kb = kstep * 32 + kg * 8;
    short8v ah = __builtin_nontemporal_load((const short8v*)&arh[kb]);
    short8v al = __builtin_nontemporal_load((const short8v*)&arl[kb]);

    const size_t bbase = ((size_t)kstep * 7 * 64 + lane) * 8;
    short8v Bh[7], Bl[7];
#pragma unroll
    for (int nf = 0; nf < 7; ++nf) {
      Bh[nf] = *(const short8v*)&ch[bbase + (size_t)nf * 512];
      Bl[nf] = *(const short8v*)&cl[bbase + (size_t)nf * 512];
    }
#pragma unroll
    for (int nf = 0; nf < 7; ++nf) {
      acc[nf] = __builtin_amdgcn_mfma_f32_16x16x32_bf16(ah, Bh[nf], acc[nf], 0, 0, 0);
      acc[nf] = __builtin_amdgcn_mfma_f32_16x16x32_bf16(ah, Bl[nf], acc[nf], 0, 0, 0);
      acc[nf] = __builtin_amdgcn_mfma_f32_16x16x32_bf16(al, Bh[nf], acc[nf], 0, 0, 0);
    }
  }

#pragma unroll
  for (int nf = 0; nf < 7; ++nf) {
    const int row = row0 + kg * 4;
#pragma unroll
    for (int r = 0; r < 4; ++r) {
      if (row + r < n) {
        float v = acc[nf][r];
        size_t ro = (size_t)(row + r) * 16 + rA;
        if (nf == 0) {
          s0f[ro] = v;
        } else if (nf < 4) {
          Pa1[ro * 4 + (nf - 1)] = __float2half(v);
          if (nf == 1) Pa1[ro * 4 + 3] = __float2half(0.f);
        } else {
          Pa2[ro * 4 + (nf - 4)] = __float2half(v);
          if (nf == 4) Pa2[ro * 4 + 3] = __float2half(0.f);
        }
      }
    }
  }
}

// ---------------- radix partition ----------------
__global__ __launch_bounds__(256) void part_hist(
    const int* __restrict__ r1, int e1, const int* __restrict__ r2, int e2,
    int* __restrict__ g1, int* __restrict__ g2,
    int* __restrict__ bt1, int* __restrict__ bt2, int nbk) {
  const int m = blockIdx.y;
  const int NB = m ? NB2 : NB1;
  const int b = blockIdx.x;
  if (b >= NB) return;
  const int* rows = m ? r2 : r1;
  const int E = m ? e2 : e1;
  int* g = m ? g2 : g1;
  int* bt = m ? bt2 : bt1;
  __shared__ int h[512];
  for (int i = threadIdx.x; i < nbk; i += 256) h[i] = 0;
  __syncthreads();
  const int ch = (E + NB - 1) / NB;
  const int lo = b * ch, hi = min(lo + ch, E);
  for (int i = lo + threadIdx.x; i < hi; i += 256)
    atomicAdd(&h[rows[i] >> BKLG], 1);
  __syncthreads();
  for (int k = threadIdx.x; k < nbk; k += 256) {
    g[(size_t)k * NB + b] = h[k];
    if (h[k]) atomicAdd(&bt[k], h[k]);
  }
}

// scan bucket totals -> exclusive bucket bases (1 block per matrix)
__global__ __launch_bounds__(256) void scan_bt(
    const int* __restrict__ bt1, int* __restrict__ ebt1,
    const int* __restrict__ bt2, int* __restrict__ ebt2, int nbk) {
  const int* bt = blockIdx.x ? bt2 : bt1;
  int* ebt = blockIdx.x ? ebt2 : ebt1;
  __shared__ int sh[256];
  const int t = threadIdx.x;
  int v = (t < nbk) ? bt[t] : 0;
  sh[t] = v;
  __syncthreads();
  for (int d = 1; d < 256; d <<= 1) {
    int u = (t >= d) ? sh[t - d] : 0;
    __syncthreads();
    sh[t] += u;
    __syncthreads();
  }
  if (t < nbk) ebt[t] = sh[t] - v;
}

// per-bucket scan of per-block counts -> global offsets (parallel over buckets)
__global__ __launch_bounds__(256) void offs_scan(
    int* __restrict__ g1, const int* __restrict__ ebt1,
    int* __restrict__ g2, const int* __restrict__ ebt2, int nbk) {
  const int m = blockIdx.y;
  const int NB = m ? NB2 : NB1;
  int* g = m ? g2 : g1;
  const int* ebt = m ? ebt2 : ebt1;
  const int k = blockIdx.x;
  __shared__ int sh[256];
  const int t = threadIdx.x;
  int v = (t < NB) ? g[(size_t)k * NB + t] : 0;
  sh[t] = v;
  __syncthreads();
  for (int d = 1; d < 256; d <<= 1) {
    int u = (t >= d) ? sh[t - d] : 0;
    __syncthreads();
    sh[t] += u;
    __syncthreads();
  }
  if (t < NB) g[(size_t)k * NB + t] = ebt[k] + sh[t] - v;
}

// scatter: block b's writes to bucket k form one contiguous run (write-amp ~1x)
__global__ __launch_bounds__(256) void part_scatter(
    const int* __restrict__ r1, const int* __restrict__ c1, const float* __restrict__ v1, int e1,
    const int* __restrict__ r2, const int* __restrict__ c2, const float* __restrict__ v2, int e2,
    const int* __restrict__ g1, const int* __restrict__ g2,
    int2* __restrict__ pack1, int2* __restrict__ pack2, int nbk) {
  const int m = blockIdx.y;
  const int NB = m ? NB2 : NB1;
  const int b = blockIdx.x;
  if (b >= NB) return;
  const int* rows = m ? r2 : r1;
  const int* cols = m ? c2 : c1;
  const float* vals = m ? v2 : v1;
  const int E = m ? e2 : e1;
  const int* g = m ? g2 : g1;
  int2* pack = m ? pack2 : pack1;
  __shared__ int lcur[512];
  for (int k = threadIdx.x; k < nbk; k += 256) lcur[k] = g[(size_t)k * NB + b];
  __syncthreads();
  const int ch = (E + NB - 1) / NB;
  const int lo = b * ch, hi = min(lo + ch, E);
  for (int i = lo + threadIdx.x; i < hi; i += 256) {
    int r = rows[i];
    int pos = atomicAdd(&lcur[r >> BKLG], 1);
    unsigned u = (unsigned)(vals[i] * 65536.0f);
    if (u > 65535u) u = 65535u;
    pack[pos] = make_int2(cols[i] | ((r & (BKW - 1)) << 16), (int)u);
  }
}

// per-bucket LDS counting sort (256 rows) -> row-sorted 4B edges + per-row rp
__global__ __launch_bounds__(256) void bucket_sort(
    const int2* __restrict__ pack1, const int* __restrict__ g1,
    unsigned* __restrict__ srt1, int* __restrict__ rp1, int e1,
    const int2* __restrict__ pack2, const int* __restrict__ g2,
    unsigned* __restrict__ srt2, int* __restrict__ rp2, int e2,
    int n, int nbk) {
  const int m = blockIdx.y;
  const int NB = m ? NB2 : NB1;
  const int2* pack = m ? pack2 : pack1;
  const int* g = m ? g2 : g1;
  unsigned* srt = m ? srt2 : srt1;
  int* rp = m ? rp2 : rp1;
  const int E = m ? e2 : e1;
  const int k = blockIdx.x;
  const int base = g[(size_t)k * NB];
  const int end = (k + 1 < nbk) ? g[(size_t)(k + 1) * NB] : E;
  __shared__ int lcnt[256], lws[256], lcur[256];
  const int t = threadIdx.x;
  lcnt[t] = 0;
  __syncthreads();
  const int* packx = (const int*)pack;
  for (int i = base + t; i < end; i += 256)
    atomicAdd(&lcnt[(packx[2 * i] >> 16) & (BKW - 1)], 1);
  __syncthreads();
  int s = lcnt[t];
  lws[t] = s;
  __syncthreads();
  for (int d = 1; d < 256; d <<= 1) {
    int v = (t >= d) ? lws[t - d] : 0;
    __syncthreads();
    lws[t] += v;
    __syncthreads();
  }
  int excl = base + lws[t] - s;
  lcur[t] = excl;
  int row = k * BKW + t;
  if (row < n) rp[row] = excl;
  if (k == nbk - 1 && t == 0) rp[n] = E;
  __syncthreads();
  for (int i = base + t; i < end; i += 256) {
    int2 e = pack[i];
    int pos = atomicAdd(&lcur[(e.x >> 16) & (BKW - 1)], 1);
    srt[pos] = (unsigned)(e.x & 0xFFFF) | ((unsigned)e.y << 16);
  }
}

__device__ __forceinline__ float dec_val(unsigned e) {
  return ((float)(e >> 16) + 0.5f) * (1.0f / 65536.0f);
}

// ---------------- fused SpMM (both matrices, 48-wide) + combine ----------------
__global__ __launch_bounds__(256) void spmm48_both(
    const unsigned* __restrict__ srt1, const int* __restrict__ rp1,
    const unsigned* __restrict__ srt2, const int* __restrict__ rp2,
    const __half* __restrict__ Pa1, const __half* __restrict__ Pa2,
    const float* __restrict__ s0f, float* __restrict__ wsum,
    __half* __restrict__ m3h, __half* __restrict__ m4h, int n) {
  const int row = blockIdx.x * 4 + (threadIdx.x >> 6);
  if (row >= n) return;
  const int lane = threadIdx.x & 63;
  const int c = lane & 15, g = lane >> 4;
  float a0 = 0.f, a1 = 0.f, a2 = 0.f, b0 = 0.f, b1 = 0.f, b2 = 0.f;
  {
    const int j0 = rp1[row], j1 = rp1[row + 1];
    if (j1 > j0) {
      const int nit = (j1 - j0 + 15) >> 4;
      int j = j0 + g;
      for (int it = 0; it < nit; ++it, j += 16) {
        int jj0 = min(j, j1 - 1), jj1 = min(j + 4, j1 - 1);
        int jj2 = min(j + 8, j1 - 1), jj3 = min(j + 12, j1 - 1);
        unsigned e0 = __builtin_nontemporal_load(&srt1[jj0]);
        unsigned e1 = __builtin_nontemporal_load(&srt1[jj1]);
        unsigned e2 = __builtin_nontemporal_load(&srt1[jj2]);
        unsigned e3 = __builtin_nontemporal_load(&srt1[jj3]);
        float2 r0 = *(const float2*)(Pa1 + ((size_t)(e0 & 0xFFFF) * 16 + c) * 4);
        float2 r1 = *(const float2*)(Pa1 + ((size_t)(e1 & 0xFFFF) * 16 + c) * 4);
        float2 r2 = *(const float2*)(Pa1 + ((size_t)(e2 & 0xFFFF) * 16 + c) * 4);
        float2 r3 = *(const float2*)(Pa1 + ((size_t)(e3 & 0xFFFF) * 16 + c) * 4);
        float v0 = (j < j1) ? dec_val(e0) : 0.f;
        float v1 = (j + 4 < j1) ? dec_val(e1) : 0.f;
        float v2 = (j + 8 < j1) ? dec_val(e2) : 0.f;
        float v3 = (j + 12 < j1) ? dec_val(e3) : 0.f;
        float2 f00 = __half22float2(*(__half2*)&r0.x), f01 = __half22float2(*(__half2*)&r0.y);
        float2 f10 = __half22float2(*(__half2*)&r1.x), f11 = __half22float2(*(__half2*)&r1.y);
        float2 f20 = __half22float2(*(__half2*)&r2.x), f21 = __half22float2(*(__half2*)&r2.y);
        float2 f30 = __half22float2(*(__half2*)&r3.x), f31 = __half22float2(*(__half2*)&r3.y);
        a0 += v0 * f00.x + v1 * f10.x + v2 * f20.x + v3 * f30.x;
        a1 += v0 * f00.y + v1 * f10.y + v2 * f20.y + v3 * f30.y;
        a2 += v0 * f01.x + v1 * f11.x + v2 * f21.x + v3 * f31.x;
      }
    }
  }
  {
    const int j0 = rp2[row], j1 = rp2[row + 1];
    if (j1 > j0) {
      const int nit = (j1 - j0 + 15) >> 4;
      int j = j0 + g;
      for (int it = 0; it < nit; ++it, j += 16) {
        int jj0 = min(j, j1 - 1), jj1 = min(j + 4, j1 - 1);
        int jj2 = min(j + 8, j1 - 1), jj3 = min(j + 12, j1 - 1);
        unsigned e0 = __builtin_nontemporal_load(&srt2[jj0]);
        unsigned e1 = __builtin_nontemporal_load(&srt2[jj1]);
        unsigned e2 = __builtin_nontemporal_load(&srt2[jj2]);
        unsigned e3 = __builtin_nontemporal_load(&srt2[jj3]);
        float2 r0 = *(const float2*)(Pa2 + ((size_t)(e0 & 0xFFFF) * 16 + c) * 4);
        float2 r1 = *(const float2*)(Pa2 + ((size_t)(e1 & 0xFFFF) * 16 + c) * 4);
        float2 r2 = *(const float2*)(Pa2 + ((size_t)(e2 & 0xFFFF) * 16 + c) * 4);
        float2 r3 = *(const float2*)(Pa2 + ((size_t)(e3 & 0xFFFF) * 16 + c) * 4);
        float v0 = (j < j1) ? dec_val(e0) : 0.f;
        float v1 = (j + 4 < j1) ? dec_val(e1) : 0.f;
        float v2 = (j + 8 < j1) ? dec_val(e2) : 0.f;
        float v3 = (j + 12 < j1) ? dec_val(e3) : 0.f;
        float2 f00 = __half22float2(*(__half2*)&r0.x), f01 = __half22float2(*(__half2*)&r0.y);
        float2 f10 = __half22float2(*(__half2*)&r1.x), f11 = __half22float2(*(__half2*)&r1.y);
        float2 f20 = __half22float2(*(__half2*)&r2.x), f21 = __half22float2(*(__half2*)&r2.y);
        float2 f30 = __half22float2(*(__half2*)&r3.x), f31 = __half22float2(*(__half2*)&r3.y);
        b0 += v0 * f00.x + v1 * f10.x + v2 * f20.x + v3 * f30.x;
        b1 += v0 * f00.y + v1 * f10.y + v2 * f20.y + v3 * f30.y;
        b2 += v0 * f01.x + v1 * f11.x + v2 * f21.x + v3 * f31.x;
      }
    }
  }
  a0 += __shfl_xor(a0, 16); a0 += __shfl_xor(a0, 32);
  a1 += __shfl_xor(a1, 16); a1 += __shfl_xor(a1, 32);
  a2 += __shfl_xor(a2, 16); a2 += __shfl_xor(a2, 32);
  b0 += __shfl_xor(b0, 16); b0 += __shfl_xor(b0, 32);
  b1 += __shfl_xor(b1, 16); b1 += __shfl_xor(b1, 32);
  b2 += __shfl_xor(b2, 16); b2 += __shfl_xor(b2, 32);
  if (g == 0) {
    size_t ro = (size_t)row * 16 + c;
    wsum[ro] = s0f[ro] + a0 + b0;
    m3h[ro] = __float2half(a1 + b1);
    m4h[ro] = __float2half(a2 + b2);
  }
}

// ---------------- final: logits = wsum + A1@m3 + A2@m4; softmax ----------------
__global__ __launch_bounds__(256) void final_spmm_softmax(
    const unsigned* __restrict__ srt1, const int* __restrict__ rp1,
    const unsigned* __restrict__ srt2, const int* __restrict__ rp2,
    const float* __restrict__ wsum, const __half* __restrict__ m3h,
    const __half* __restrict__ m4h, float* __restrict__ out, int n) {
  const int row = blockIdx.x * 4 + (threadIdx.x >> 6);
  if (row >= n) return;
  const int lane = threadIdx.x & 63;
  const int c = lane & 15, g = lane >> 4;
  float accA = 0.f, accB = 0.f;
  {
    const int j0 = rp1[row], j1 = rp1[row + 1];
    if (j1 > j0) {
      const int nit = (j1 - j0 + 15) >> 4;
      int j = j0 + g;
      for (int it = 0; it < nit; ++it, j += 16) {
        int jj0 = min(j, j1 - 1), jj1 = min(j + 4, j1 - 1);
        int jj2 = min(j + 8, j1 - 1), jj3 = min(j + 12, j1 - 1);
        unsigned e0 = __builtin_nontemporal_load(&srt1[jj0]);
        unsigned e1 = __builtin_nontemporal_load(&srt1[jj1]);
        unsigned e2 = __builtin_nontemporal_load(&srt1[jj2]);
        unsigned e3 = __builtin_nontemporal_load(&srt1[jj3]);
        float g0 = __half2float(m3h[(size_t)(e0 & 0xFFFF) * 16 + c]);
        float g1 = __half2float(m3h[(size_t)(e1 & 0xFFFF) * 16 + c]);
        float g2 = __half2float(m3h[(size_t)(e2 & 0xFFFF) * 16 + c]);
        float g3 = __half2float(m3h[(size_t)(e3 & 0xFFFF) * 16 + c]);
        float v0 = (j < j1) ? dec_val(e0) : 0.f;
        float v1 = (j + 4 < j1) ? dec_val(e1) : 0.f;
        float v2 = (j + 8 < j1) ? dec_val(e2) : 0.f;
        float v3 = (j + 12 < j1) ? dec_val(e3) : 0.f;
        accA += v0 * g0 + v1 * g1 + v2 * g2 + v3 * g3;
      }
    }
  }
  {
    const int j0 = rp2[row], j1 = rp2[row + 1];
    if (j1 > j0) {
      const int nit = (j1 - j0 + 15) >> 4;
      int j = j0 + g;
      for (int it = 0; it < nit; ++it, j += 16) {
        int jj0 = min(j, j1 - 1), jj1 = min(j + 4, j1 - 1);
        int jj2 = min(j + 8, j1 - 1), jj3 = min(j + 12, j1 - 1);
        unsigned e0 = __builtin_nontemporal_load(&srt2[jj0]);
        unsigned e1 = __builtin_nontemporal_load(&srt2[jj1]);
        unsigned e2 = __builtin_nontemporal_load(&srt2[jj2]);
        unsigned e3 = __builtin_nontemporal_load(&srt2[jj3]);
        float g0 = __half2float(m4h[(size_t)(e0 & 0xFFFF) * 16 + c]);
        float g1 = __half2float(m4h[(size_t)(e1 & 0xFFFF) * 16 + c]);
        float g2 = __half2float(m4h[(size_t)(e2 & 0xFFFF) * 16 + c]);
        float g3 = __half2float(m4h[(size_t)(e3 & 0xFFFF) * 16 + c]);
        float v0 = (j < j1) ? dec_val(e0) : 0.f;
        float v1 = (j + 4 < j1) ? dec_val(e1) : 0.f;
        float v2 = (j + 8 < j1) ? dec_val(e2) : 0.f;
        float v3 = (j + 12 < j1) ? dec_val(e3) : 0.f;
        accB += v0 * g0 + v1 * g1 + v2 * g2 + v3 * g3;
      }
    }
  }
  accA += __shfl_xor(accA, 16); accA += __shfl_xor(accA, 32);
  accB += __shfl_xor(accB, 16); accB += __shfl_xor(accB, 32);
  float logit = wsum[(size_t)row * 16 + c] + accA + accB;
  float m = logit;
#pragma unroll
  for (int off = 1; off < 16; off <<= 1) m = fmaxf(m, __shfl_xor(m, off));
  float e = __expf(logit - m);
  float s = e;
#pragma unroll
  for (int off = 1; off < 16; off <<= 1) s += __shfl_xor(s, off);
  float p = e / s;
  if (lane < 16) out[(size_t)row * NCLS + lane] = p;
}

extern "C" void kernel_launch(void* const* d_in, const int* in_sizes, int n_in,
                              void* d_out, int out_size, void* d_ws, size_t ws_size,
                              hipStream_t stream) {
  const float* x   = (const float*)d_in[0];
  const int*   a1r = (const int*)d_in[1];
  const int*   a1c = (const int*)d_in[2];
  const float* a1v = (const float*)d_in[3];
  const int*   a2r = (const int*)d_in[4];
  const int*   a2c = (const int*)d_in[5];
  const float* a2v = (const float*)d_in[6];
  const float* we  = (const float*)d_in[7];
  const float* wc  = (const float*)d_in[8];
  const int n  = in_sizes[0] / INF;   // 50000 (<= 65536 for 16-bit col pack)
  const int e1 = in_sizes[1];         // 1,000,000
  const int e2 = in_sizes[4];         // 1,500,000
  const int nbk = (n + BKW - 1) >> BKLG;   // 196 buckets of 256 rows

  // ---- workspace layout (~80 MB) ----
  char* w = (char*)d_ws;
  size_t off = 0;
  unsigned short* r0h = (unsigned short*)(w + off); off += (size_t)n * HID * 2;     // 12.8 MB
  unsigned short* r0l = (unsigned short*)(w + off); off += (size_t)n * HID * 2;     // 12.8 MB
  float* s0f  = (float*)(w + off); off += (size_t)n * 16 * 4;                       //  3.2 MB
  __half* Pa1 = (__half*)(w + off); off += (size_t)n * 64 * 2;                      //  6.4 MB
  __half* Pa2 = (__half*)(w + off); off += (size_t)n * 64 * 2;                      //  6.4 MB
  float* wsum = (float*)(w + off); off += (size_t)n * 16 * 4;                       //  3.2 MB
  __half* m3h = (__half*)(w + off); off += (size_t)n * 16 * 2;                      //  1.6 MB
  __half* m4h = (__half*)(w + off); off += (size_t)n * 16 * 2;                      //  1.6 MB
  int2* pack1 = (int2*)(w + off);  off += (size_t)e1 * 8;                           //  8 MB
  int2* pack2 = (int2*)(w + off);  off += (size_t)e2 * 8;                           // 12 MB
  unsigned* srt1 = (unsigned*)(w + off); off += (size_t)e1 * 4;                     //  4 MB
  unsigned* srt2 = (unsigned*)(w + off); off += (size_t)e2 * 4;                     //  6 MB
  unsigned short* wefh = (unsigned short*)(w + off); off += (size_t)512 * HID * 2;  // 128 KB
  unsigned short* wefl = (unsigned short*)(w + off); off += (size_t)512 * HID * 2;  // 128 KB
  unsigned short* wcfh = (unsigned short*)(w + off); off += (size_t)HID * PW * 2;   //  28 KB
  unsigned short* wcfl = (unsigned short*)(w + off); off += (size_t)HID * PW * 2;   //  28 KB
  int* g1 = (int*)(w + off); off += (size_t)512 * NB1 * 4;                          // 256 KB
  int* g2 = (int*)(w + off); off += (size_t)512 * NB2 * 4;                          // 384 KB
  int* rp1 = (int*)(w + off); off += (size_t)(n + 1) * 4;
  int* rp2 = (int*)(w + off); off += (size_t)(n + 1) * 4;
  int* bt1  = (int*)(w + off); off += (size_t)512 * 4;   // bucket totals (zeroed in prep_w)
  int* bt2  = (int*)(w + off); off += (size_t)512 * 4;
  int* ebt1 = (int*)(w + off); off += (size_t)512 * 4;   // exclusive bucket bases
  int* ebt2 = (int*)(w + off); off += (size_t)512 * 4;

  prep_w<<<312, 256, 0, stream>>>(we, wc, wefh, wefl, wcfh, wcfl, bt1);
  embed_mfma<<<(n + 127) / 128, 256, 0, stream>>>(x, wefh, wefl, r0h, r0l, n);
  proj_mfma<<<(n + 63) / 64, 256, 0, stream>>>(r0h, r0l, wcfh, wcfl, s0f, Pa1, Pa2, n);

  part_hist<<<dim3(NB2, 2), 256, 0, stream>>>(a1r, e1, a2r, e2, g1, g2, bt1, bt2, nbk);
  scan_bt<<<2, 256, 0, stream>>>(bt1, ebt1, bt2, ebt2, nbk);
  offs_scan<<<dim3(nbk, 2), 256, 0, stream>>>(g1, ebt1, g2, ebt2, nbk);
  part_scatter<<<dim3(NB2, 2), 256, 0, stream>>>(
      a1r, a1c, a1v, e1, a2r, a2c, a2v, e2, g1, g2, pack1, pack2, nbk);
  bucket_sort<<<dim3(nbk, 2), 256, 0, stream>>>(
      pack1, g1, srt1, rp1, e1, pack2, g2, srt2, rp2, e2, n, nbk);

  spmm48_both<<<(n + 3) / 4, 256, 0, stream>>>(
      srt1, rp1, srt2, rp2, Pa1, Pa2, s0f, wsum, m3h, m4h, n);
  final_spmm_softmax<<<(n + 3) / 4, 256, 0, stream>>>(
      srt1, rp1, srt2, rp2, wsum, m3h, m4h, (float*)d_out, n);
}

// Round 20
// 228.663 us; speedup vs baseline: 1.1245x; 1.0066x over previous
//
#include <hip/hip_runtime.h>
#include <hip/hip_fp16.h>

#define HID 128
#define INF 500
#define NCLS 16
#define PW  112    // projected width: [s0 | p1 q3a q4a | p2 q3b q4b]
#define BKLG 8
#define BKW 256    // rows per bucket
#define NB1 128    // partition blocks, matrix 1
#define NB2 192    // partition blocks, matrix 2

typedef __attribute__((ext_vector_type(8))) short short8v;
typedef __attribute__((ext_vector_type(4))) float f32x4;
typedef __attribute__((ext_vector_type(4))) float f4v;   // native vec for nontemporal builtins

// split fp32 into hi (truncated bf16) + lo (bf16 of remainder)
__device__ __forceinline__ void split_bf16(float v, unsigned short& h, unsigned short& l) {
  unsigned u = __float_as_uint(v);
  h = (unsigned short)(u >> 16);
  float hf = __uint_as_float(u & 0xFFFF0000u);
  l = (unsigned short)(__float_as_uint(v - hf) >> 16);
}

__device__ __forceinline__ void cvt8v(f4v c0, f4v c1, short8v& h8, short8v& l8) {
#pragma unroll
  for (int j = 0; j < 8; ++j) {
    float v = (j < 4) ? c0[j] : c1[j - 4];
    unsigned short h, l;
    split_bf16(v, h, l);
    h8[j] = (short)h;
    l8[j] = (short)l;
  }
}

// ---------------- weight prep (also zeroes bucket-total counters) ----------------
__global__ __launch_bounds__(256) void prep_w(
    const float* __restrict__ we, const float* __restrict__ wc,
    unsigned short* __restrict__ wh, unsigned short* __restrict__ wl,
    unsigned short* __restrict__ ch, unsigned short* __restrict__ cl,
    int* __restrict__ btz) {
  const int bid = blockIdx.x;
  if (bid == 0) {
    for (int i = threadIdx.x; i < 1024; i += 256) btz[i] = 0;
  }
  if (bid < 256) {
    int idx = bid * 256 + threadIdx.x;     // < 512*128
    int k = idx >> 7, nn = idx & 127;
    float v = (k < INF) ? we[k * HID + nn] : 0.f;
    unsigned short h, l;
    split_bf16(v, h, l);
    int kstep = k >> 5, ks = k & 31;
    int lane = (nn & 15) | ((ks >> 3) << 4);
    int j = ks & 7, nf = nn >> 4;
    size_t o = (((size_t)(kstep * 8 + nf)) * 64 + lane) * 8 + j;
    wh[o] = h;
    wl[o] = l;
  } else {
    int idx = (bid - 256) * 256 + threadIdx.x;
    if (idx >= HID * PW) return;
    int k = idx / PW, np = idx % PW;
    int o = np >> 4;
    int blk = (o == 0) ? 0 : ((o < 4) ? (2 * o - 1) : (2 * o - 6));
    float v = wc[(blk * HID + k) * NCLS + (np & 15)];
    unsigned short h, l;
    split_bf16(v, h, l);
    int kstep = k >> 5, ks = k & 31;
    int lane = (np & 15) | ((ks >> 3) << 4);
    int j = ks & 7, nf = np >> 4;
    size_t of = (((size_t)(kstep * 7 + nf)) * 64 + lane) * 8 + j;
    ch[of] = h;
    cl[of] = l;
  }
}

// ---------------- embed MFMA: r0 = relu(x @ we), bf16x3 ----------------
// 128 rows/block, 256 threads = 4 waves x 32 rows.
__global__ __launch_bounds__(256) void embed_mfma(
    const float* __restrict__ x, const unsigned short* __restrict__ wh,
    const unsigned short* __restrict__ wl, unsigned short* __restrict__ r0h,
    unsigned short* __restrict__ r0l, int n) {
  const int tid = threadIdx.x;
  const int wave = tid >> 6, lane = tid & 63;
  const int row0 = blockIdx.x * 128;
  const int rA = lane & 15, kg = lane >> 4;

  __shared__ float xs[128][68];   // 34.8 KB

  f32x4 acc[2][8];
#pragma unroll
  for (int rf = 0; rf < 2; ++rf)
#pragma unroll
    for (int nf = 0; nf < 8; ++nf)
#pragma unroll
      for (int r = 0; r < 4; ++r) acc[rf][nf][r] = 0.f;

  f4v pf[8];
#define LOAD_TILE(kt)                                                         \
  {                                                                           \
    const int k0_ = (kt) * 64;                                                \
    _Pragma("unroll")                                                         \
    for (int q = 0; q < 8; ++q) {                                             \
      int i_ = tid + q * 256;                                                 \
      int r_ = i_ >> 4, pos_ = i_ & 15;                                       \
      int gr_ = min(row0 + r_, n - 1);                                        \
      int gk_ = k0_ + pos_ * 4;                                               \
      pf[q] = (gk_ + 4 <= INF)                                                \
                  ? __builtin_nontemporal_load(                               \
                        (const f4v*)&x[(size_t)gr_ * INF + gk_])              \
                  : (f4v)(0.f);                                               \
    }                                                                         \
  }

  LOAD_TILE(0);
  for (int kt = 0; kt < 8; ++kt) {
#pragma unroll
    for (int q = 0; q < 8; ++q) {
      int i = tid + q * 256;
      *(f4v*)&xs[i >> 4][(i & 15) * 4] = pf[q];
    }
    __syncthreads();
    if (kt < 7) LOAD_TILE(kt + 1);

#pragma unroll
    for (int kh2 = 0; kh2 < 2; ++kh2) {
      const int kb = kh2 * 32 + kg * 8;
      short8v ah[2], al[2];
#pragma unroll
      for (int rf = 0; rf < 2; ++rf) {
        const int rl = wave * 32 + rf * 16 + rA;
        f4v c0 = *(const f4v*)&xs[rl][kb];
        f4v c1 = *(const f4v*)&xs[rl][kb + 4];
        cvt8v(c0, c1, ah[rf], al[rf]);
      }
      const size_t bbase = ((size_t)((kt * 2 + kh2) * 8) * 64 + lane) * 8;
      short8v Bh[8], Bl[8];
#pragma unroll
      for (int nf = 0; nf < 8; ++nf) {
        Bh[nf] = *(const short8v*)&wh[bbase + (size_t)nf * 512];
        Bl[nf] = *(const short8v*)&wl[bbase + (size_t)nf * 512];
      }
#pragma unroll
      for (int nf = 0; nf < 8; ++nf)
#pragma unroll
        for (int rf = 0; rf < 2; ++rf) {
          acc[rf][nf] = __builtin_amdgcn_mfma_f32_16x16x32_bf16(ah[rf], Bh[nf], acc[rf][nf], 0, 0, 0);
          acc[rf][nf] = __builtin_amdgcn_mfma_f32_16x16x32_bf16(ah[rf], Bl[nf], acc[rf][nf], 0, 0, 0);
          acc[rf][nf] = __builtin_amdgcn_mfma_f32_16x16x32_bf16(al[rf], Bh[nf], acc[rf][nf], 0, 0, 0);
        }
    }
    __syncthreads();
  }
#undef LOAD_TILE

#pragma unroll
  for (int rf = 0; rf < 2; ++rf)
#pragma unroll
    for (int nf = 0; nf < 8; ++nf) {
      const int row = row0 + wave * 32 + rf * 16 + kg * 4;
      const int col = nf * 16 + rA;
#pragma unroll
      for (int r = 0; r < 4; ++r) {
        if (row + r < n) {
          float v = fmaxf(acc[rf][nf][r], 0.f);
          unsigned short h, l;
          split_bf16(v, h, l);
          r0h[(size_t)(row + r) * HID + col] = h;
          r0l[(size_t)(row + r) * HID + col] = l;
        }
      }
    }
}

// ---------------- proj MFMA: [s0|Pa1|Pa2] = r0 @ wcP, bf16x3, 4 waves x 16 rows ----------------
__global__ __launch_bounds__(256) void proj_mfma(
    const unsigned short* __restrict__ r0h, const unsigned short* __restrict__ r0l,
    const unsigned short* __restrict__ ch, const unsigned short* __restrict__ cl,
    float* __restrict__ s0f, __half* __restrict__ Pa1, __half* __restrict__ Pa2, int n) {
  const int wave = threadIdx.x >> 6, lane = threadIdx.x & 63;
  const int row0 = blockIdx.x * 64 + wave * 16;
  const int rA = lane & 15, kg = lane >> 4;

  f32x4 acc[7];
#pragma unroll
  for (int nf = 0; nf < 7; ++nf)
#pragma unroll
    for (int r = 0; r < 4; ++r) acc[nf][r] = 0.f;

  const unsigned short* arh = &r0h[(size_t)min(row0 + rA, n - 1) * HID];
  const unsigned short* arl = &r0l[(size_t)min(row0 + rA, n - 1) * HID];

#pragma unroll
  for (int kstep = 0; kstep < 4; ++kstep) {
    const int kb = kstep * 32 + kg * 8;
    short8v ah = __builtin_nontemporal_load((const short8v*)&arh[kb]);
    short8v al = __builtin_nontemporal_load((const short8v*)&arl[kb]);

    const size_t bbase = ((size_t)kstep * 7 * 64 + lane) * 8;
    short8v Bh[7], Bl[7];
#pragma unroll
    for (int nf = 0; nf < 7; ++nf) {
      Bh[nf] = *(const short8v*)&ch[bbase + (size_t)nf * 512];
      Bl[nf] = *(const short8v*)&cl[bbase + (size_t)nf * 512];
    }
#pragma unroll
    for (int nf = 0; nf < 7; ++nf) {
      acc[nf] = __builtin_amdgcn_mfma_f32_16x16x32_bf16(ah, Bh[nf], acc[nf], 0, 0, 0);
      acc[nf] = __builtin_amdgcn_mfma_f32_16x16x32_bf16(ah, Bl[nf], acc[nf], 0, 0, 0);
      acc[nf] = __builtin_amdgcn_mfma_f32_16x16x32_bf16(al, Bh[nf], acc[nf], 0, 0, 0);
    }
  }

#pragma unroll
  for (int nf = 0; nf < 7; ++nf) {
    const int row = row0 + kg * 4;
#pragma unroll
    for (int r = 0; r < 4; ++r) {
      if (row + r < n) {
        float v = acc[nf][r];
        size_t ro = (size_t)(row + r) * 16 + rA;
        if (nf == 0) {
          s0f[ro] = v;
        } else if (nf < 4) {
          Pa1[ro * 4 + (nf - 1)] = __float2half(v);
          if (nf == 1) Pa1[ro * 4 + 3] = __float2half(0.f);
        } else {
          Pa2[ro * 4 + (nf - 4)] = __float2half(v);
          if (nf == 4) Pa2[ro * 4 + 3] = __float2half(0.f);
        }
      }
    }
  }
}

// ---------------- radix partition ----------------
__global__ __launch_bounds__(256) void part_hist(
    const int* __restrict__ r1, int e1, const int* __restrict__ r2, int e2,
    int* __restrict__ g1, int* __restrict__ g2,
    int* __restrict__ bt1, int* __restrict__ bt2, int nbk) {
  const int m = blockIdx.y;
  const int NB = m ? NB2 : NB1;
  const int b = blockIdx.x;
  if (b >= NB) return;
  const int* rows = m ? r2 : r1;
  const int E = m ? e2 : e1;
  int* g = m ? g2 : g1;
  int* bt = m ? bt2 : bt1;
  __shared__ int h[512];
  for (int i = threadIdx.x; i < nbk; i += 256) h[i] = 0;
  __syncthreads();
  const int ch = (E + NB - 1) / NB;
  const int lo = b * ch, hi = min(lo + ch, E);
  for (int i = lo + threadIdx.x; i < hi; i += 256)
    atomicAdd(&h[rows[i] >> BKLG], 1);
  __syncthreads();
  for (int k = threadIdx.x; k < nbk; k += 256) {
    g[(size_t)k * NB + b] = h[k];
    if (h[k]) atomicAdd(&bt[k], h[k]);
  }
}

// per-bucket scan of per-block counts -> global offsets.
// Each block also recomputes the bucket-base prefix from bt locally
// (196 ints; redundant across blocks but removes the scan_bt launch).
__global__ __launch_bounds__(256) void offs_scan(
    int* __restrict__ g1, const int* __restrict__ bt1,
    int* __restrict__ g2, const int* __restrict__ bt2, int nbk) {
  const int m = blockIdx.y;
  const int NB = m ? NB2 : NB1;
  int* g = m ? g2 : g1;
  const int* bt = m ? bt2 : bt1;
  const int k = blockIdx.x;
  __shared__ int sh[256];
  __shared__ int ebtk;
  const int t = threadIdx.x;

  // phase 1: scan bucket totals; thread k captures its exclusive prefix
  int bv = (t < nbk) ? bt[t] : 0;
  sh[t] = bv;
  __syncthreads();
  for (int d = 1; d < 256; d <<= 1) {
    int u = (t >= d) ? sh[t - d] : 0;
    __syncthreads();
    sh[t] += u;
    __syncthreads();
  }
  if (t == k) ebtk = sh[t] - bv;   // exclusive bucket base (k < nbk <= 256)
  __syncthreads();

  // phase 2: scan this bucket's per-block counts
  int v = (t < NB) ? g[(size_t)k * NB + t] : 0;
  sh[t] = v;
  __syncthreads();
  for (int d = 1; d < 256; d <<= 1) {
    int u = (t >= d) ? sh[t - d] : 0;
    __syncthreads();
    sh[t] += u;
    __syncthreads();
  }
  if (t < NB) g[(size_t)k * NB + t] = ebtk + sh[t] - v;
}

// scatter: block b's writes to bucket k form one contiguous run (write-amp ~1x)
__global__ __launch_bounds__(256) void part_scatter(
    const int* __restrict__ r1, const int* __restrict__ c1, const float* __restrict__ v1, int e1,
    const int* __restrict__ r2, const int* __restrict__ c2, const float* __restrict__ v2, int e2,
    const int* __restrict__ g1, const int* __restrict__ g2,
    int2* __restrict__ pack1, int2* __restrict__ pack2, int nbk) {
  const int m = blockIdx.y;
  const int NB = m ? NB2 : NB1;
  const int b = blockIdx.x;
  if (b >= NB) return;
  const int* rows = m ? r2 : r1;
  const int* cols = m ? c2 : c1;
  const float* vals = m ? v2 : v1;
  const int E = m ? e2 : e1;
  const int* g = m ? g2 : g1;
  int2* pack = m ? pack2 : pack1;
  __shared__ int lcur[512];
  for (int k = threadIdx.x; k < nbk; k += 256) lcur[k] = g[(size_t)k * NB + b];
  __syncthreads();
  const int ch = (E + NB - 1) / NB;
  const int lo = b * ch, hi = min(lo + ch, E);
  for (int i = lo + threadIdx.x; i < hi; i += 256) {
    int r = rows[i];
    int pos = atomicAdd(&lcur[r >> BKLG], 1);
    unsigned u = (unsigned)(vals[i] * 65536.0f);
    if (u > 65535u) u = 65535u;
    pack[pos] = make_int2(cols[i] | ((r & (BKW - 1)) << 16), (int)u);
  }
}

// per-bucket LDS counting sort (256 rows) -> row-sorted 4B edges + per-row rp
__global__ __launch_bounds__(256) void bucket_sort(
    const int2* __restrict__ pack1, const int* __restrict__ g1,
    unsigned* __restrict__ srt1, int* __restrict__ rp1, int e1,
    const int2* __restrict__ pack2, const int* __restrict__ g2,
    unsigned* __restrict__ srt2, int* __restrict__ rp2, int e2,
    int n, int nbk) {
  const int m = blockIdx.y;
  const int NB = m ? NB2 : NB1;
  const int2* pack = m ? pack2 : pack1;
  const int* g = m ? g2 : g1;
  unsigned* srt = m ? srt2 : srt1;
  int* rp = m ? rp2 : rp1;
  const int E = m ? e2 : e1;
  const int k = blockIdx.x;
  const int base = g[(size_t)k * NB];
  const int end = (k + 1 < nbk) ? g[(size_t)(k + 1) * NB] : E;
  __shared__ int lcnt[256], lws[256], lcur[256];
  const int t = threadIdx.x;
  lcnt[t] = 0;
  __syncthreads();
  const int* packx = (const int*)pack;
  for (int i = base + t; i < end; i += 256)
    atomicAdd(&lcnt[(packx[2 * i] >> 16) & (BKW - 1)], 1);
  __syncthreads();
  int s = lcnt[t];
  lws[t] = s;
  __syncthreads();
  for (int d = 1; d < 256; d <<= 1) {
    int v = (t >= d) ? lws[t - d] : 0;
    __syncthreads();
    lws[t] += v;
    __syncthreads();
  }
  int excl = base + lws[t] - s;
  lcur[t] = excl;
  int row = k * BKW + t;
  if (row < n) rp[row] = excl;
  if (k == nbk - 1 && t == 0) rp[n] = E;
  __syncthreads();
  for (int i = base + t; i < end; i += 256) {
    int2 e = pack[i];
    int pos = atomicAdd(&lcur[(e.x >> 16) & (BKW - 1)], 1);
    srt[pos] = (unsigned)(e.x & 0xFFFF) | ((unsigned)e.y << 16);
  }
}

__device__ __forceinline__ float dec_val(unsigned e) {
  return ((float)(e >> 16) + 0.5f) * (1.0f / 65536.0f);
}

// ---------------- fused SpMM (both matrices, 48-wide) + combine ----------------
__global__ __launch_bounds__(256) void spmm48_both(
    const unsigned* __restrict__ srt1, const int* __restrict__ rp1,
    const unsigned* __restrict__ srt2, const int* __restrict__ rp2,
    const __half* __restrict__ Pa1, const __half* __restrict__ Pa2,
    const float* __restrict__ s0f, float* __restrict__ wsum,
    __half* __restrict__ m3h, __half* __restrict__ m4h, int n) {
  const int row = blockIdx.x * 4 + (threadIdx.x >> 6);
  if (row >= n) return;
  const int lane = threadIdx.x & 63;
  const int c = lane & 15, g = lane >> 4;
  float a0 = 0.f, a1 = 0.f, a2 = 0.f, b0 = 0.f, b1 = 0.f, b2 = 0.f;
  {
    const int j0 = rp1[row], j1 = rp1[row + 1];
    if (j1 > j0) {
      const int nit = (j1 - j0 + 15) >> 4;
      int j = j0 + g;
      for (int it = 0; it < nit; ++it, j += 16) {
        int jj0 = min(j, j1 - 1), jj1 = min(j + 4, j1 - 1);
        int jj2 = min(j + 8, j1 - 1), jj3 = min(j + 12, j1 - 1);
        unsigned e0 = __builtin_nontemporal_load(&srt1[jj0]);
        unsigned e1 = __builtin_nontemporal_load(&srt1[jj1]);
        unsigned e2 = __builtin_nontemporal_load(&srt1[jj2]);
        unsigned e3 = __builtin_nontemporal_load(&srt1[jj3]);
        float2 r0 = *(const float2*)(Pa1 + ((size_t)(e0 & 0xFFFF) * 16 + c) * 4);
        float2 r1 = *(const float2*)(Pa1 + ((size_t)(e1 & 0xFFFF) * 16 + c) * 4);
        float2 r2 = *(const float2*)(Pa1 + ((size_t)(e2 & 0xFFFF) * 16 + c) * 4);
        float2 r3 = *(const float2*)(Pa1 + ((size_t)(e3 & 0xFFFF) * 16 + c) * 4);
        float v0 = (j < j1) ? dec_val(e0) : 0.f;
        float v1 = (j + 4 < j1) ? dec_val(e1) : 0.f;
        float v2 = (j + 8 < j1) ? dec_val(e2) : 0.f;
        float v3 = (j + 12 < j1) ? dec_val(e3) : 0.f;
        float2 f00 = __half22float2(*(__half2*)&r0.x), f01 = __half22float2(*(__half2*)&r0.y);
        float2 f10 = __half22float2(*(__half2*)&r1.x), f11 = __half22float2(*(__half2*)&r1.y);
        float2 f20 = __half22float2(*(__half2*)&r2.x), f21 = __half22float2(*(__half2*)&r2.y);
        float2 f30 = __half22float2(*(__half2*)&r3.x), f31 = __half22float2(*(__half2*)&r3.y);
        a0 += v0 * f00.x + v1 * f10.x + v2 * f20.x + v3 * f30.x;
        a1 += v0 * f00.y + v1 * f10.y + v2 * f20.y + v3 * f30.y;
        a2 += v0 * f01.x + v1 * f11.x + v2 * f21.x + v3 * f31.x;
      }
    }
  }
  {
    const int j0 = rp2[row], j1 = rp2[row + 1];
    if (j1 > j0) {
      const int nit = (j1 - j0 + 15) >> 4;
      int j = j0 + g;
      for (int it = 0; it < nit; ++it, j += 16) {
        int jj0 = min(j, j1 - 1), jj1 = min(j + 4, j1 - 1);
        int jj2 = min(j + 8, j1 - 1), jj3 = min(j + 12, j1 - 1);
        unsigned e0 = __builtin_nontemporal_load(&srt2[jj0]);
        unsigned e1 = __builtin_nontemporal_load(&srt2[jj1]);
        unsigned e2 = __builtin_nontemporal_load(&srt2[jj2]);
        unsigned e3 = __builtin_nontemporal_load(&srt2[jj3]);
        float2 r0 = *(const float2*)(Pa2 + ((size_t)(e0 & 0xFFFF) * 16 + c) * 4);
        float2 r1 = *(const float2*)(Pa2 + ((size_t)(e1 & 0xFFFF) * 16 + c) * 4);
        float2 r2 = *(const float2*)(Pa2 + ((size_t)(e2 & 0xFFFF) * 16 + c) * 4);
        float2 r3 = *(const float2*)(Pa2 + ((size_t)(e3 & 0xFFFF) * 16 + c) * 4);
        float v0 = (j < j1) ? dec_val(e0) : 0.f;
        float v1 = (j + 4 < j1) ? dec_val(e1) : 0.f;
        float v2 = (j + 8 < j1) ? dec_val(e2) : 0.f;
        float v3 = (j + 12 < j1) ? dec_val(e3) : 0.f;
        float2 f00 = __half22float2(*(__half2*)&r0.x), f01 = __half22float2(*(__half2*)&r0.y);
        float2 f10 = __half22float2(*(__half2*)&r1.x), f11 = __half22float2(*(__half2*)&r1.y);
        float2 f20 = __half22float2(*(__half2*)&r2.x), f21 = __half22float2(*(__half2*)&r2.y);
        float2 f30 = __half22float2(*(__half2*)&r3.x), f31 = __half22float2(*(__half2*)&r3.y);
        b0 += v0 * f00.x + v1 * f10.x + v2 * f20.x + v3 * f30.x;
        b1 += v0 * f00.y + v1 * f10.y + v2 * f20.y + v3 * f30.y;
        b2 += v0 * f01.x + v1 * f11.x + v2 * f21.x + v3 * f31.x;
      }
    }
  }
  a0 += __shfl_xor(a0, 16); a0 += __shfl_xor(a0, 32);
  a1 += __shfl_xor(a1, 16); a1 += __shfl_xor(a1, 32);
  a2 += __shfl_xor(a2, 16); a2 += __shfl_xor(a2, 32);
  b0 += __shfl_xor(b0, 16); b0 += __shfl_xor(b0, 32);
  b1 += __shfl_xor(b1, 16); b1 += __shfl_xor(b1, 32);
  b2 += __shfl_xor(b2, 16); b2 += __shfl_xor(b2, 32);
  if (g == 0) {
    size_t ro = (size_t)row * 16 + c;
    wsum[ro] = s0f[ro] + a0 + b0;
    m3h[ro] = __float2half(a1 + b1);
    m4h[ro] = __float2half(a2 + b2);
  }
}

// ---------------- final: logits = wsum + A1@m3 + A2@m4; softmax ----------------
__global__ __launch_bounds__(256) void final_spmm_softmax(
    const unsigned* __restrict__ srt1, const int* __restrict__ rp1,
    const unsigned* __restrict__ srt2, const int* __restrict__ rp2,
    const float* __restrict__ wsum, const __half* __restrict__ m3h,
    const __half* __restrict__ m4h, float* __restrict__ out, int n) {
  const int row = blockIdx.x * 4 + (threadIdx.x >> 6);
  if (row >= n) return;
  const int lane = threadIdx.x & 63;
  const int c = lane & 15, g = lane >> 4;
  float accA = 0.f, accB = 0.f;
  {
    const int j0 = rp1[row], j1 = rp1[row + 1];
    if (j1 > j0) {
      const int nit = (j1 - j0 + 15) >> 4;
      int j = j0 + g;
      for (int it = 0; it < nit; ++it, j += 16) {
        int jj0 = min(j, j1 - 1), jj1 = min(j + 4, j1 - 1);
        int jj2 = min(j + 8, j1 - 1), jj3 = min(j + 12, j1 - 1);
        unsigned e0 = __builtin_nontemporal_load(&srt1[jj0]);
        unsigned e1 = __builtin_nontemporal_load(&srt1[jj1]);
        unsigned e2 = __builtin_nontemporal_load(&srt1[jj2]);
        unsigned e3 = __builtin_nontemporal_load(&srt1[jj3]);
        float g0 = __half2float(m3h[(size_t)(e0 & 0xFFFF) * 16 + c]);
        float g1 = __half2float(m3h[(size_t)(e1 & 0xFFFF) * 16 + c]);
        float g2 = __half2float(m3h[(size_t)(e2 & 0xFFFF) * 16 + c]);
        float g3 = __half2float(m3h[(size_t)(e3 & 0xFFFF) * 16 + c]);
        float v0 = (j < j1) ? dec_val(e0) : 0.f;
        float v1 = (j + 4 < j1) ? dec_val(e1) : 0.f;
        float v2 = (j + 8 < j1) ? dec_val(e2) : 0.f;
        float v3 = (j + 12 < j1) ? dec_val(e3) : 0.f;
        accA += v0 * g0 + v1 * g1 + v2 * g2 + v3 * g3;
      }
    }
  }
  {
    const int j0 = rp2[row], j1 = rp2[row + 1];
    if (j1 > j0) {
      const int nit = (j1 - j0 + 15) >> 4;
      int j = j0 + g;
      for (int it = 0; it < nit; ++it, j += 16) {
        int jj0 = min(j, j1 - 1), jj1 = min(j + 4, j1 - 1);
        int jj2 = min(j + 8, j1 - 1), jj3 = min(j + 12, j1 - 1);
        unsigned e0 = __builtin_nontemporal_load(&srt2[jj0]);
        unsigned e1 = __builtin_nontemporal_load(&srt2[jj1]);
        unsigned e2 = __builtin_nontemporal_load(&srt2[jj2]);
        unsigned e3 = __builtin_nontemporal_load(&srt2[jj3]);
        float g0 = __half2float(m4h[(size_t)(e0 & 0xFFFF) * 16 + c]);
        float g1 = __half2float(m4h[(size_t)(e1 & 0xFFFF) * 16 + c]);
        float g2 = __half2float(m4h[(size_t)(e2 & 0xFFFF) * 16 + c]);
        float g3 = __half2float(m4h[(size_t)(e3 & 0xFFFF) * 16 + c]);
        float v0 = (j < j1) ? dec_val(e0) : 0.f;
        float v1 = (j + 4 < j1) ? dec_val(e1) : 0.f;
        float v2 = (j + 8 < j1) ? dec_val(e2) : 0.f;
        float v3 = (j + 12 < j1) ? dec_val(e3) : 0.f;
        accB += v0 * g0 + v1 * g1 + v2 * g2 + v3 * g3;
      }
    }
  }
  accA += __shfl_xor(accA, 16); accA += __shfl_xor(accA, 32);
  accB += __shfl_xor(accB, 16); accB += __shfl_xor(accB, 32);
  float logit = wsum[(size_t)row * 16 + c] + accA + accB;
  float m = logit;
#pragma unroll
  for (int off = 1; off < 16; off <<= 1) m = fmaxf(m, __shfl_xor(m, off));
  float e = __expf(logit - m);
  float s = e;
#pragma unroll
  for (int off = 1; off < 16; off <<= 1) s += __shfl_xor(s, off);
  float p = e / s;
  if (lane < 16) out[(size_t)row * NCLS + lane] = p;
}

extern "C" void kernel_launch(void* const* d_in, const int* in_sizes, int n_in,
                              void* d_out, int out_size, void* d_ws, size_t ws_size,
                              hipStream_t stream) {
  const float* x   = (const float*)d_in[0];
  const int*   a1r = (const int*)d_in[1];
  const int*   a1c = (const int*)d_in[2];
  const float* a1v = (const float*)d_in[3];
  const int*   a2r = (const int*)d_in[4];
  const int*   a2c = (const int*)d_in[5];
  const float* a2v = (const float*)d_in[6];
  const float* we  = (const float*)d_in[7];
  const float* wc  = (const float*)d_in[8];
  const int n  = in_sizes[0] / INF;   // 50000 (<= 65536 for 16-bit col pack)
  const int e1 = in_sizes[1];         // 1,000,000
  const int e2 = in_sizes[4];         // 1,500,000
  const int nbk = (n + BKW - 1) >> BKLG;   // 196 buckets of 256 rows

  // ---- workspace layout (~80 MB) ----
  char* w = (char*)d_ws;
  size_t off = 0;
  unsigned short* r0h = (unsigned short*)(w + off); off += (size_t)n * HID * 2;     // 12.8 MB
  unsigned short* r0l = (unsigned short*)(w + off); off += (size_t)n * HID * 2;     // 12.8 MB
  float* s0f  = (float*)(w + off); off += (size_t)n * 16 * 4;                       //  3.2 MB
  __half* Pa1 = (__half*)(w + off); off += (size_t)n * 64 * 2;                      //  6.4 MB
  __half* Pa2 = (__half*)(w + off); off += (size_t)n * 64 * 2;                      //  6.4 MB
  float* wsum = (float*)(w + off); off += (size_t)n * 16 * 4;                       //  3.2 MB
  __half* m3h = (__half*)(w + off); off += (size_t)n * 16 * 2;                      //  1.6 MB
  __half* m4h = (__half*)(w + off); off += (size_t)n * 16 * 2;                      //  1.6 MB
  int2* pack1 = (int2*)(w + off);  off += (size_t)e1 * 8;                           //  8 MB
  int2* pack2 = (int2*)(w + off);  off += (size_t)e2 * 8;                           // 12 MB
  unsigned* srt1 = (unsigned*)(w + off); off += (size_t)e1 * 4;                     //  4 MB
  unsigned* srt2 = (unsigned*)(w + off); off += (size_t)e2 * 4;                     //  6 MB
  unsigned short* wefh = (unsigned short*)(w + off); off += (size_t)512 * HID * 2;  // 128 KB
  unsigned short* wefl = (unsigned short*)(w + off); off += (size_t)512 * HID * 2;  // 128 KB
  unsigned short* wcfh = (unsigned short*)(w + off); off += (size_t)HID * PW * 2;   //  28 KB
  unsigned short* wcfl = (unsigned short*)(w + off); off += (size_t)HID * PW * 2;   //  28 KB
  int* g1 = (int*)(w + off); off += (size_t)512 * NB1 * 4;                          // 256 KB
  int* g2 = (int*)(w + off); off += (size_t)512 * NB2 * 4;                          // 384 KB
  int* rp1 = (int*)(w + off); off += (size_t)(n + 1) * 4;
  int* rp2 = (int*)(w + off); off += (size_t)(n + 1) * 4;
  int* bt1  = (int*)(w + off); off += (size_t)512 * 4;   // bucket totals (zeroed in prep_w)
  int* bt2  = (int*)(w + off); off += (size_t)512 * 4;

  prep_w<<<312, 256, 0, stream>>>(we, wc, wefh, wefl, wcfh, wcfl, bt1);
  embed_mfma<<<(n + 127) / 128, 256, 0, stream>>>(x, wefh, wefl, r0h, r0l, n);
  proj_mfma<<<(n + 63) / 64, 256, 0, stream>>>(r0h, r0l, wcfh, wcfl, s0f, Pa1, Pa2, n);

  part_hist<<<dim3(NB2, 2), 256, 0, stream>>>(a1r, e1, a2r, e2, g1, g2, bt1, bt2, nbk);
  offs_scan<<<dim3(nbk, 2), 256, 0, stream>>>(g1, bt1, g2, bt2, nbk);
  part_scatter<<<dim3(NB2, 2), 256, 0, stream>>>(
      a1r, a1c, a1v, e1, a2r, a2c, a2v, e2, g1, g2, pack1, pack2, nbk);
  bucket_sort<<<dim3(nbk, 2), 256, 0, stream>>>(
      pack1, g1, srt1, rp1, e1, pack2, g2, srt2, rp2, e2, n, nbk);

  spmm48_both<<<(n + 3) / 4, 256, 0, stream>>>(
      srt1, rp1, srt2, rp2, Pa1, Pa2, s0f, wsum, m3h, m4h, n);
  final_spmm_softmax<<<(n + 3) / 4, 256, 0, stream>>>(
      srt1, rp1, srt2, rp2, wsum, m3h, m4h, (float*)d_out, n);
}